// Round 5
// baseline (211.726 us; speedup 1.0000x reference)
//
#include <hip/hip_runtime.h>
#include <hip/hip_bf16.h>

// DisenGCN forward — 3-dispatch chain:
//   K1: gather + proj(L0) + zero(acc, bars)          [normal launch]
//   K2: route x3 (L0, internal barriers) + proj(L1)  [cooperative]
//   K3: route x3 (L1, internal barriers) + finalize  [cooperative]
//
// Sides: 0=user, 1=item. n_rows = n_neigh+1 (4097). Row = 64 f32.
// Combined row index rr in [0, 2*n_rows): side = rr >= n_rows.
// Route wave layout: g = lane>>4 (row subgroup), c = lane&15 (float4 chunk),
//                    k = c>>2 (channel).
//
// ws (floats): z[2*n_rows*64], zn[2*n_rows*64], acc[12*64], bars[8 ints].
// acc slot s = L*3+t, addr (s*2+side)*64. Cross-block acc reads use
// device-scope atomicAdd(p, 0.f) (XCD-L2-stale-proof); bulk z/zn crossings
// ride dispatch boundaries only.

#define NB 256   // blocks for K2/K3 (co-resident: 1/CU, cooperative launch)

__device__ __forceinline__ float g4sum(float v) {
    v += __shfl_xor(v, 1, 64);
    v += __shfl_xor(v, 2, 64);
    return v;
}
__device__ __forceinline__ float g16sum(float v) {
    v += __shfl_xor(v, 1, 64);
    v += __shfl_xor(v, 2, 64);
    v += __shfl_xor(v, 4, 64);
    v += __shfl_xor(v, 8, 64);
    return v;
}

__device__ __forceinline__ void devbar(int* __restrict__ ctr, int nb) {
    __syncthreads();
    if (threadIdx.x == 0) {
        __threadfence();                       // release prior writes/atomics
        atomicAdd(ctr, 1);
        while (atomicAdd(ctr, 0) < nb) __builtin_amdgcn_s_sleep(2);
        __threadfence();
    }
    __syncthreads();
}

// proj one row held as float4-chunks-in-lanes: lane chunk c=lane&15 has elems
// 4c..4c+3 (replicated over the 4 16-lane groups). Output elem m=k*16+d in lane m.
__device__ __forceinline__ float proj_row4(const float xa[4],
                                           const float* __restrict__ W,
                                           const float* __restrict__ b, int lane) {
    const int k = lane >> 4, d = lane & 15;
    float sum = b[k * 16 + d];
    const float* __restrict__ Wp = W + k * 1024 + d;   // W[k][i][d]
#pragma unroll
    for (int i = 0; i < 64; ++i)
        sum = fmaf(__shfl(xa[i & 3], i >> 2, 64), Wp[i * 16], sum);
    return fmaxf(sum, 0.f);
}

// ---- K1: gather + proj L0 (1 row/wave) + zero acc/bars ----
__global__ __launch_bounds__(256) void k1_gather_proj(
    const int* __restrict__ user, const int* __restrict__ item,
    const int* __restrict__ nu, const int* __restrict__ ni,
    const float* __restrict__ Gu, const float* __restrict__ Gi,
    const float* __restrict__ W0, const float* __restrict__ b0,
    float* __restrict__ z, float* __restrict__ zn,
    float* __restrict__ acc, int* __restrict__ bars, int n_rows)
{
    if (blockIdx.x == 0) {
        for (int i = threadIdx.x; i < 12 * 64; i += blockDim.x) acc[i] = 0.f;
        if (threadIdx.x < 8) bars[threadIdx.x] = 0;
    }
    const int lane = threadIdx.x & 63;
    const int wv   = threadIdx.x >> 6;
    const int rr   = blockIdx.x * 4 + wv;
    if (rr >= 2 * n_rows) return;
    const int side = rr >= n_rows;
    const int n    = rr - side * n_rows;
    const int c    = lane & 15;

    int idx; const float* G;
    if (n == 0) { idx = side ? item[0] : user[0];       G = side ? Gi : Gu; }
    else        { idx = side ? ni[n - 1] : nu[n - 1];   G = side ? Gu : Gi; }
    const float4 xv = ((const float4*)(G + (size_t)idx * 64))[c];
    const float xa[4] = {xv.x, xv.y, xv.z, xv.w};

    const float zv = proj_row4(xa, W0, b0, lane);
    z[(size_t)rr * 64 + lane] = zv;
    const float nrm = fmaxf(sqrtf(g16sum(zv * zv)), 1e-12f);
    zn[(size_t)rr * 64 + lane] = zv / nrm;
}

// One routing iteration body. Ego comes from sEgo (LDS, already normalized).
__device__ __forceinline__ void route_iter(
    const float4* __restrict__ zn4,  // this side's zn, float4 view
    const float* __restrict__ sEgo,
    float* __restrict__ acc_dst,     // acc + (slot*2+side)*64
    float4 (&red)[4][64],
    int bg, int wv, int lane, int n_neigh)
{
    const int g = lane >> 4, c = lane & 15, k = c >> 2;
    const float4 e4 = ((const float4*)sEgo)[c];

    float4 a4 = {0.f, 0.f, 0.f, 0.f};
    const int nwv = (NB / 2) * 4;            // waves per side
    const int wid = bg * 4 + wv;
    for (int base = wid; ; base += nwv) {
        const int n = 1 + base * 4 + g;
        if (n > n_neigh) break;
        const float4 z4 = zn4[(size_t)n * 16 + c];
        float dp = g4sum(z4.x * e4.x + z4.y * e4.y + z4.z * e4.z + z4.w * e4.w);
        const int bl = lane & 48;
        const float d0 = __shfl(dp, bl, 64),     d1 = __shfl(dp, bl + 4, 64);
        const float d2 = __shfl(dp, bl + 8, 64), d3 = __shfl(dp, bl + 12, 64);
        const float mx = fmaxf(fmaxf(d0, d1), fmaxf(d2, d3));
        const float e0 = expf(d0 - mx), e1 = expf(d1 - mx);
        const float e2 = expf(d2 - mx), e3 = expf(d3 - mx);
        const float eo = (k == 0) ? e0 : (k == 1) ? e1 : (k == 2) ? e2 : e3;
        const float pk = eo / (e0 + e1 + e2 + e3);
        a4.x = fmaf(pk, z4.x, a4.x); a4.y = fmaf(pk, z4.y, a4.y);
        a4.z = fmaf(pk, z4.z, a4.z); a4.w = fmaf(pk, z4.w, a4.w);
    }

    red[wv][lane] = a4;
    __syncthreads();
    if (wv == 0) {
        float4 s = red[0][lane];
        const float4 s1 = red[1][lane], s2 = red[2][lane], s3 = red[3][lane];
        s.x += s1.x + s2.x + s3.x; s.y += s1.y + s2.y + s3.y;
        s.z += s1.z + s2.z + s3.z; s.w += s1.w + s2.w + s3.w;
#pragma unroll
        for (int m = 16; m <= 32; m <<= 1) {
            s.x += __shfl_xor(s.x, m, 64); s.y += __shfl_xor(s.y, m, 64);
            s.z += __shfl_xor(s.z, m, 64); s.w += __shfl_xor(s.w, m, 64);
        }
        if (lane < 16) {
            float* dst = acc_dst + lane * 4;
            atomicAdd(dst + 0, s.x); atomicAdd(dst + 1, s.y);
            atomicAdd(dst + 2, s.z); atomicAdd(dst + 3, s.w);
        }
    }
    __syncthreads();  // red[] reuse guard
}

// Build normalized ego in sEgo. t==0: zn row 0 (plain load, dispatch-ordered).
// t>0: atomic-read prev acc slot (cross-XCD safe).
__device__ __forceinline__ void build_ego(
    const float* __restrict__ zn_side, float* __restrict__ acc,
    float* __restrict__ sEgo, int t, int L, int side, int wv, int lane)
{
    if (wv == 0) {
        float e = (t == 0) ? zn_side[lane]
                           : atomicAdd(&acc[((L * 3 + t - 1) * 2 + side) * 64 + lane], 0.f);
        const float nrm = fmaxf(sqrtf(g16sum(e * e)), 1e-12f);
        sEgo[lane] = e / nrm;
    }
    __syncthreads();
}

// ---- K2: route x3 (L0) + proj L1 ----
__global__ __launch_bounds__(256) void k2_route_proj(
    const float* __restrict__ W1, const float* __restrict__ b1,
    const float* __restrict__ z, float* __restrict__ zn,
    float* __restrict__ acc, int* __restrict__ bars, int n_neigh)
{
    const int n_rows = n_neigh + 1;
    const int lane = threadIdx.x & 63;
    const int wv   = threadIdx.x >> 6;
    const int side = blockIdx.x & 1;
    const int bg   = blockIdx.x >> 1;
    const float* __restrict__ zn_side = zn + (size_t)side * n_rows * 64;
    const float4* __restrict__ zn4 = (const float4*)zn_side;

    __shared__ float4 red[4][64];
    __shared__ float sEgo[64];

    for (int t = 0; t < 3; ++t) {
        build_ego(zn_side, acc, sEgo, t, 0, side, wv, lane);
        route_iter(zn4, sEgo, acc + (t * 2 + side) * 64, red, bg, wv, lane, n_neigh);
        devbar(&bars[t], NB);
    }

    // proj L1 over all rows (combined index), zn updated in place.
    for (int rr = blockIdx.x * 4 + wv; rr < 2 * n_rows; rr += NB * 4) {
        const int sd = rr >= n_rows;
        const int n  = rr - sd * n_rows;
        const int c  = lane & 15;
        float xa[4];
        if (n == 0) {
            float* src = acc + (2 * 2 + sd) * 64;   // L0 t2 routed, raw
#pragma unroll
            for (int j = 0; j < 4; ++j) xa[j] = atomicAdd(&src[4 * c + j], 0.f);
        } else {
            const float4 xv = ((const float4*)(z + (size_t)rr * 64))[c];
            xa[0] = xv.x; xa[1] = xv.y; xa[2] = xv.z; xa[3] = xv.w;
        }
        const float zv = proj_row4(xa, W1, b1, lane);
        const float nrm = fmaxf(sqrtf(g16sum(zv * zv)), 1e-12f);
        zn[(size_t)rr * 64 + lane] = zv / nrm;
    }
}

// ---- K3: route x3 (L1) + finalize ----
__global__ __launch_bounds__(256) void k3_route_final(
    const float* __restrict__ zn, float* __restrict__ acc,
    int* __restrict__ bars, float* __restrict__ out, int n_neigh)
{
    const int n_rows = n_neigh + 1;
    const int lane = threadIdx.x & 63;
    const int wv   = threadIdx.x >> 6;
    const int side = blockIdx.x & 1;
    const int bg   = blockIdx.x >> 1;
    const float* __restrict__ zn_side = zn + (size_t)side * n_rows * 64;
    const float4* __restrict__ zn4 = (const float4*)zn_side;

    __shared__ float4 red[4][64];
    __shared__ float sEgo[64];

    for (int t = 0; t < 3; ++t) {
        build_ego(zn_side, acc, sEgo, t, 1, side, wv, lane);
        route_iter(zn4, sEgo, acc + ((3 + t) * 2 + side) * 64, red, bg, wv, lane, n_neigh);
        devbar(&bars[3 + t], NB);
    }

    if (blockIdx.x == 0 && wv == 0) {
        const float u = atomicAdd(&acc[(5 * 2 + 0) * 64 + lane], 0.f);
        const float v = atomicAdd(&acc[(5 * 2 + 1) * 64 + lane], 0.f);
        out[1 + lane]  = u;
        out[65 + lane] = v;
        float p = u * v;
#pragma unroll
        for (int s = 32; s >= 1; s >>= 1) p += __shfl_xor(p, s, 64);
        if (lane == 0) out[0] = p;
    }
}

extern "C" void kernel_launch(void* const* d_in, const int* in_sizes, int n_in,
                              void* d_out, int out_size, void* d_ws, size_t ws_size,
                              hipStream_t stream) {
    const int*   user       = (const int*)d_in[0];
    const int*   item       = (const int*)d_in[1];
    const int*   neigh_user = (const int*)d_in[2];
    const int*   neigh_item = (const int*)d_in[3];
    const float* Gu         = (const float*)d_in[4];
    const float* Gi         = (const float*)d_in[5];
    const float* W0         = (const float*)d_in[6];
    const float* b0         = (const float*)d_in[7];
    const float* W1         = (const float*)d_in[8];
    const float* b1         = (const float*)d_in[9];
    float* out = (float*)d_out;

    int n_neigh = in_sizes[2];
    int n_rows  = n_neigh + 1;

    float* z    = (float*)d_ws;
    float* zn   = z  + (size_t)2 * n_rows * 64;
    float* acc  = zn + (size_t)2 * n_rows * 64;
    int*   bars = (int*)(acc + 12 * 64);

    // K1 (normal launch)
    const dim3 g1((2 * n_rows + 3) / 4);
    hipLaunchKernelGGL(k1_gather_proj, g1, dim3(256), 0, stream,
                       user, item, neigh_user, neigh_item, Gu, Gi, W0, b0,
                       z, zn, acc, bars, n_rows);

    // K2 (cooperative)
    {
        void* args[] = {(void*)&W1, (void*)&b1, (void*)&z, (void*)&zn,
                        (void*)&acc, (void*)&bars, (void*)&n_neigh};
        hipLaunchCooperativeKernel((const void*)k2_route_proj,
                                   dim3(NB), dim3(256), args, 0, stream);
    }
    // K3 (cooperative)
    {
        void* args[] = {(void*)&zn, (void*)&acc, (void*)&bars,
                        (void*)&out, (void*)&n_neigh};
        hipLaunchCooperativeKernel((const void*)k3_route_final,
                                   dim3(NB), dim3(256), args, 0, stream);
    }
}

// Round 7
// 170.070 us; speedup vs baseline: 1.2449x; 1.2449x over previous
//
#include <hip/hip_runtime.h>
#include <hip/hip_bf16.h>

// DisenGCN forward — single cooperative kernel + tiny memset.
// 128 blocks x 512 threads (8 waves). Sides: even blocks = user, odd = item.
// Per side: 64 blocks x 8 waves = 512 waves; neighbors 1..4096 = 1024 chunks
// of 4 rows; each wave owns chunks {wsid, wsid+512} -> 8 rows, kept ENTIRELY
// in registers (zr raw, zn normalized; 4 floats/lane, chunk layout:
// g=lane>>4 picks row-in-chunk, c=lane&15 holds elems 4c..4c+3, k=c>>2).
// Row 0 (ego) recomputed per block by wave 0 (cheap) -> no bulk cross-block
// data at all. Only acc (12 slots x 64 f) crosses blocks:
//   writes: device atomicAdd (memory-side); reads: atomicAdd(p,0.f) RMW
//   (round-5-verified safe across XCD L2s; plain/sc1 loads are NOT trusted).
// Barriers: fence + release fetch_add arrivals on 8 spread counters; block 0
// detects via acquire load-polling and publishes a release flag; waiters
// load-poll the flag (loads can only delay, never corrupt).
//
// ws: acc[12*64] floats @0, bars[6*144] ints after; memset'd per call.
// acc slot s=L*3+t at (s*2+side)*64.

#define NB      128
#define WPB     8
#define THREADS 512

__device__ __forceinline__ float g4sum(float v) {
    v += __shfl_xor(v, 1, 64);
    v += __shfl_xor(v, 2, 64);
    return v;  // sum within 4-lane quad (one channel of one row)
}
__device__ __forceinline__ float g16sum(float v) {
    v += __shfl_xor(v, 1, 64);
    v += __shfl_xor(v, 2, 64);
    v += __shfl_xor(v, 4, 64);
    v += __shfl_xor(v, 8, 64);
    return v;  // sum within 16-lane group
}
__device__ __forceinline__ float rmw_read(float* p) {
    return atomicAdd(p, 0.0f);  // memory-side, cross-XCD safe
}

__device__ __forceinline__ void flagbar(int* __restrict__ bars, int b, bool wait_release) {
    int* base = bars + b * 144;
    __syncthreads();
    if (threadIdx.x == 0) {
        __threadfence();  // prior acc RMWs complete before arrival visible
        __hip_atomic_fetch_add(&base[(blockIdx.x & 7) * 16], 1,
                               __ATOMIC_RELEASE, __HIP_MEMORY_SCOPE_AGENT);
        if (blockIdx.x == 0) {
            int s;
            do {
                __builtin_amdgcn_s_sleep(1);
                s = 0;
#pragma unroll
                for (int j = 0; j < 8; ++j)
                    s += __hip_atomic_load(&base[j * 16], __ATOMIC_ACQUIRE,
                                           __HIP_MEMORY_SCOPE_AGENT);
            } while (s < NB);
            __threadfence();
            __hip_atomic_store(&base[8 * 16], 1, __ATOMIC_RELEASE,
                               __HIP_MEMORY_SCOPE_AGENT);
        } else if (wait_release) {
            while (!__hip_atomic_load(&base[8 * 16], __ATOMIC_ACQUIRE,
                                      __HIP_MEMORY_SCOPE_AGENT))
                __builtin_amdgcn_s_sleep(4);
        }
        __threadfence();
    }
    __syncthreads();
}

__global__ __launch_bounds__(THREADS, 1) void disen_all(
    const int* __restrict__ user, const int* __restrict__ item,
    const int* __restrict__ nu, const int* __restrict__ ni,
    const float* __restrict__ Gu, const float* __restrict__ Gi,
    const float* __restrict__ W0, const float* __restrict__ b0,
    const float* __restrict__ W1, const float* __restrict__ b1,
    float* __restrict__ acc, int* __restrict__ bars,
    float* __restrict__ out, int n_neigh)
{
    const int tid  = threadIdx.x;
    const int lane = tid & 63;
    const int wv   = tid >> 6;
    const int side = blockIdx.x & 1;
    const int bg   = blockIdx.x >> 1;
    const int g    = lane >> 4;
    const int c    = lane & 15;
    const int k    = c >> 2;
    const int wsid = bg * WPB + wv;        // [0, 512) within side
    const int CH   = (n_neigh + 3) >> 2;   // 1024 chunks

    __shared__ float  sW[4096];            // W staged i-major: sW[i*64+m]
    __shared__ float4 red[WPB][64];
    __shared__ float  sEgo[64];

    // ---- stage W0 ----
    for (int q = tid; q < 4096; q += THREADS) {
        const int i = q >> 6, m = q & 63;
        sW[q] = W0[(m >> 4) * 1024 + i * 16 + (m & 15)];
    }
    __syncthreads();

    // ---- gather + proj L0 for my 8 rows (registers) ----
    float zr[2][4], zn[2][4];
    bool  act[2];
    {
        const float4 bv = ((const float4*)b0)[c];
#pragma unroll
        for (int cc = 0; cc < 2; ++cc) {
            const int ch = wsid + cc * 512;
            const int n  = 1 + ch * 4 + g;
            act[cc] = (ch < CH) && (n <= n_neigh);
            float xa[4] = {0.f, 0.f, 0.f, 0.f};
            if (act[cc]) {
                const int idx = side ? ni[n - 1] : nu[n - 1];
                const float* G = side ? Gu : Gi;
                const float4 xv = ((const float4*)(G + (size_t)idx * 64))[c];
                xa[0] = xv.x; xa[1] = xv.y; xa[2] = xv.z; xa[3] = xv.w;
            }
            float o[4] = {bv.x, bv.y, bv.z, bv.w};
#pragma unroll
            for (int i = 0; i < 64; ++i) {
                const float xi = __shfl(xa[i & 3], (g << 4) + (i >> 2), 64);
                const float4 w = ((const float4*)sW)[i * 16 + c];
                o[0] = fmaf(xi, w.x, o[0]); o[1] = fmaf(xi, w.y, o[1]);
                o[2] = fmaf(xi, w.z, o[2]); o[3] = fmaf(xi, w.w, o[3]);
            }
            float nsq = 0.f;
#pragma unroll
            for (int j = 0; j < 4; ++j) {
                o[j] = fmaxf(o[j], 0.f);
                zr[cc][j] = o[j];
                nsq = fmaf(o[j], o[j], nsq);
            }
            const float inv = 1.f / fmaxf(sqrtf(g4sum(nsq)), 1e-12f);
#pragma unroll
            for (int j = 0; j < 4; ++j) zn[cc][j] = o[j] * inv;
        }
    }

    // ---- L0 row-0 ego, per block (wave 0) ----
    if (wv == 0) {
        const int idx0 = side ? item[0] : user[0];
        const float* G0 = side ? Gi : Gu;
        const float4 xv = ((const float4*)(G0 + (size_t)idx0 * 64))[c];
        const float xa[4] = {xv.x, xv.y, xv.z, xv.w};
        float sum = b0[lane];
#pragma unroll
        for (int i = 0; i < 64; ++i)
            sum = fmaf(__shfl(xa[i & 3], i >> 2, 64), sW[i * 64 + lane], sum);
        sum = fmaxf(sum, 0.f);
        sEgo[lane] = sum / fmaxf(sqrtf(g16sum(sum * sum)), 1e-12f);
    }
    __syncthreads();

    auto route_to = [&](int slot) {
        const float4 e4 = ((const float4*)sEgo)[c];
        float4 a4 = {0.f, 0.f, 0.f, 0.f};
#pragma unroll
        for (int cc = 0; cc < 2; ++cc) {
            if (!act[cc]) continue;
            float dp = g4sum(zn[cc][0] * e4.x + zn[cc][1] * e4.y +
                             zn[cc][2] * e4.z + zn[cc][3] * e4.w);
            const int bl = g << 4;
            const float d0 = __shfl(dp, bl, 64),     d1 = __shfl(dp, bl + 4, 64);
            const float d2 = __shfl(dp, bl + 8, 64), d3 = __shfl(dp, bl + 12, 64);
            const float mx = fmaxf(fmaxf(d0, d1), fmaxf(d2, d3));
            const float e0 = expf(d0 - mx), e1 = expf(d1 - mx);
            const float e2 = expf(d2 - mx), e3 = expf(d3 - mx);
            const float eo = (k == 0) ? e0 : (k == 1) ? e1 : (k == 2) ? e2 : e3;
            const float pk = eo / (e0 + e1 + e2 + e3);
            a4.x = fmaf(pk, zn[cc][0], a4.x);
            a4.y = fmaf(pk, zn[cc][1], a4.y);
            a4.z = fmaf(pk, zn[cc][2], a4.z);
            a4.w = fmaf(pk, zn[cc][3], a4.w);
        }
        red[wv][lane] = a4;
        __syncthreads();
        if (wv == 0) {
            float4 s = red[0][lane];
#pragma unroll
            for (int j = 1; j < WPB; ++j) {
                const float4 t = red[j][lane];
                s.x += t.x; s.y += t.y; s.z += t.z; s.w += t.w;
            }
#pragma unroll
            for (int m = 16; m <= 32; m <<= 1) {
                s.x += __shfl_xor(s.x, m, 64); s.y += __shfl_xor(s.y, m, 64);
                s.z += __shfl_xor(s.z, m, 64); s.w += __shfl_xor(s.w, m, 64);
            }
            if (lane < 16) {
                float* dst = acc + (slot * 2 + side) * 64 + lane * 4;
                atomicAdd(dst + 0, s.x); atomicAdd(dst + 1, s.y);
                atomicAdd(dst + 2, s.z); atomicAdd(dst + 3, s.w);
            }
        }
        __syncthreads();
    };

    auto ego_from = [&](int slot) {
        if (wv == 0) {
            const float e = rmw_read(&acc[(slot * 2 + side) * 64 + lane]);
            sEgo[lane] = e / fmaxf(sqrtf(g16sum(e * e)), 1e-12f);
        }
        __syncthreads();
    };

    // ---- layer 0 routing ----
    route_to(0); flagbar(bars, 0, true);
    ego_from(0); route_to(1); flagbar(bars, 1, true);
    ego_from(1); route_to(2); flagbar(bars, 2, true);

    // ---- layer 1: restage W1, proj my rows from zr regs ----
    for (int q = tid; q < 4096; q += THREADS) {
        const int i = q >> 6, m = q & 63;
        sW[q] = W1[(m >> 4) * 1024 + i * 16 + (m & 15)];
    }
    __syncthreads();
    {
        const float4 bv = ((const float4*)b1)[c];
#pragma unroll
        for (int cc = 0; cc < 2; ++cc) {
            if (!act[cc]) continue;
            float o[4] = {bv.x, bv.y, bv.z, bv.w};
#pragma unroll
            for (int i = 0; i < 64; ++i) {
                const float xi = __shfl(zr[cc][i & 3], (g << 4) + (i >> 2), 64);
                const float4 w = ((const float4*)sW)[i * 16 + c];
                o[0] = fmaf(xi, w.x, o[0]); o[1] = fmaf(xi, w.y, o[1]);
                o[2] = fmaf(xi, w.z, o[2]); o[3] = fmaf(xi, w.w, o[3]);
            }
            float nsq = 0.f;
#pragma unroll
            for (int j = 0; j < 4; ++j) {
                o[j] = fmaxf(o[j], 0.f);
                nsq = fmaf(o[j], o[j], nsq);
            }
            const float inv = 1.f / fmaxf(sqrtf(g4sum(nsq)), 1e-12f);
#pragma unroll
            for (int j = 0; j < 4; ++j) zn[cc][j] = o[j] * inv;
        }
    }

    // ---- L1 row-0 ego: input = routed L0 t2 (slot 2, raw), RMW-read ----
    if (wv == 0) {
        const float x = rmw_read(&acc[(2 * 2 + side) * 64 + lane]);
        float xa[4];
#pragma unroll
        for (int j = 0; j < 4; ++j) xa[j] = __shfl(x, (lane & 15) * 4 + j, 64);
        float sum = b1[lane];
#pragma unroll
        for (int i = 0; i < 64; ++i)
            sum = fmaf(__shfl(xa[i & 3], i >> 2, 64), sW[i * 64 + lane], sum);
        sum = fmaxf(sum, 0.f);
        sEgo[lane] = sum / fmaxf(sqrtf(g16sum(sum * sum)), 1e-12f);
    }
    __syncthreads();

    // ---- layer 1 routing ----
    route_to(3); flagbar(bars, 3, true);
    ego_from(3); route_to(4); flagbar(bars, 4, true);
    ego_from(4); route_to(5); flagbar(bars, 5, false);  // last: arrival-only for waiters

    // ---- finalize (block 0 has waited for all arrivals) ----
    if (blockIdx.x == 0 && wv == 0) {
        const float u = rmw_read(&acc[(5 * 2 + 0) * 64 + lane]);
        const float v = rmw_read(&acc[(5 * 2 + 1) * 64 + lane]);
        out[1 + lane]  = u;
        out[65 + lane] = v;
        float p = u * v;
#pragma unroll
        for (int s = 32; s >= 1; s >>= 1) p += __shfl_xor(p, s, 64);
        if (lane == 0) out[0] = p;
    }
}

extern "C" void kernel_launch(void* const* d_in, const int* in_sizes, int n_in,
                              void* d_out, int out_size, void* d_ws, size_t ws_size,
                              hipStream_t stream) {
    const int*   user       = (const int*)d_in[0];
    const int*   item       = (const int*)d_in[1];
    const int*   neigh_user = (const int*)d_in[2];
    const int*   neigh_item = (const int*)d_in[3];
    const float* Gu         = (const float*)d_in[4];
    const float* Gi         = (const float*)d_in[5];
    const float* W0         = (const float*)d_in[6];
    const float* b0         = (const float*)d_in[7];
    const float* W1         = (const float*)d_in[8];
    const float* b1         = (const float*)d_in[9];
    float* out = (float*)d_out;

    int n_neigh = in_sizes[2];

    float* acc  = (float*)d_ws;
    int*   bars = (int*)(acc + 12 * 64);

    // zero acc (3072 B) + bars (3456 B)
    hipMemsetAsync(d_ws, 0, 12 * 64 * 4 + 6 * 144 * 4, stream);

    void* args[] = {
        (void*)&user, (void*)&item, (void*)&neigh_user, (void*)&neigh_item,
        (void*)&Gu, (void*)&Gi, (void*)&W0, (void*)&b0, (void*)&W1, (void*)&b1,
        (void*)&acc, (void*)&bars, (void*)&out, (void*)&n_neigh
    };
    hipLaunchCooperativeKernel((const void*)disen_all,
                               dim3(NB), dim3(THREADS), args, 0, stream);
}

// Round 8
// 108.727 us; speedup vs baseline: 1.9473x; 1.5642x over previous
//
#include <hip/hip_runtime.h>
#include <hip/hip_bf16.h>

// DisenGCN forward — 4-dispatch chain, single-block-per-side routing:
//   K1: gather + proj(L0) -> z (f32), znb (bf16 normalized); zero rl1/ticket
//   K2: route x3 (L0) in-block (grid=2, 1024 thr) -> rl0 (plain)
//   K3: proj(L1) from z (row0 from rl0) -> znb
//   K4: route x3 (L1) in-block + ticket-fused finalize -> out
//
// All cross-kernel handoffs ride dispatch boundaries (runtime release/acquire).
// The only intra-dispatch cross-block exchange is K4's final dot: atomicAdd
// writes + atomicAdd(p,0) RMW reads + ticket (R4-verified safe across XCDs).
//
// Row = 64 elems. znb row stride 64 bf16 = 128 B. Route layout: 8 lanes/row,
// lane j=lane&7 holds elems [8j..8j+7]; channel k = j>>1 (16 elems = 2 lanes).
//
// ws (floats): z[2*n_rows*64] | rl0[128] | rl1[128] | ticket(int) | znb (bf16)

#define EPS 1e-12f

__device__ __forceinline__ float g16sum(float v) {
    v += __shfl_xor(v, 1, 64);
    v += __shfl_xor(v, 2, 64);
    v += __shfl_xor(v, 4, 64);
    v += __shfl_xor(v, 8, 64);
    return v;  // sum within each 16-lane group
}
__device__ __forceinline__ unsigned short f2bf(float f) {  // RNE
    unsigned int b = __float_as_uint(f);
    b += 0x7fffu + ((b >> 16) & 1u);
    return (unsigned short)(b >> 16);
}
__device__ __forceinline__ float bf2f(unsigned short u) {
    return __uint_as_float(((unsigned int)u) << 16);
}
__device__ __forceinline__ float bflo(unsigned int w) {
    return __uint_as_float(w << 16);
}
__device__ __forceinline__ float bfhi(unsigned int w) {
    return __uint_as_float(w & 0xffff0000u);
}

// proj: lane chunk c=lane&15 holds input elems 4c..4c+3 (replicated over the
// four 16-lane groups); output elem m=k*16+d in lane m.
__device__ __forceinline__ float proj_row4(const float xa[4],
                                           const float* __restrict__ W,
                                           const float* __restrict__ b, int lane) {
    const int k = lane >> 4, d = lane & 15;
    float sum = b[k * 16 + d];
    const float* __restrict__ Wp = W + k * 1024 + d;  // W[k][i][d]
#pragma unroll
    for (int i = 0; i < 64; ++i)
        sum = fmaf(__shfl(xa[i & 3], i >> 2, 64), Wp[i * 16], sum);
    return fmaxf(sum, 0.f);
}

// ---- K1: gather + proj L0 (1 row/wave); zero rl1 + ticket ----
__global__ __launch_bounds__(256) void k1_gather_proj(
    const int* __restrict__ user, const int* __restrict__ item,
    const int* __restrict__ nu, const int* __restrict__ ni,
    const float* __restrict__ Gu, const float* __restrict__ Gi,
    const float* __restrict__ W0, const float* __restrict__ b0,
    float* __restrict__ z, unsigned short* __restrict__ znb,
    float* __restrict__ rl1, int* __restrict__ ticket, int n_rows)
{
    if (blockIdx.x == 0) {
        if (threadIdx.x < 128) rl1[threadIdx.x] = 0.f;
        if (threadIdx.x == 0) *ticket = 0;
    }
    const int lane = threadIdx.x & 63;
    const int wv   = threadIdx.x >> 6;
    const int rr   = blockIdx.x * 4 + wv;
    if (rr >= 2 * n_rows) return;
    const int side = rr >= n_rows;
    const int n    = rr - side * n_rows;
    const int c    = lane & 15;

    int idx; const float* G;
    if (n == 0) { idx = side ? item[0] : user[0];     G = side ? Gi : Gu; }
    else        { idx = side ? ni[n - 1] : nu[n - 1]; G = side ? Gu : Gi; }
    const float4 xv = ((const float4*)(G + (size_t)idx * 64))[c];
    const float xa[4] = {xv.x, xv.y, xv.z, xv.w};

    const float zv = proj_row4(xa, W0, b0, lane);
    z[(size_t)rr * 64 + lane] = zv;
    const float nrm = fmaxf(sqrtf(g16sum(zv * zv)), EPS);
    znb[(size_t)rr * 64 + lane] = f2bf(zv / nrm);
}

// ---- K3: proj L1 (1 row/wave); row 0 from rl0 (raw routed L0) ----
__global__ __launch_bounds__(256) void k3_proj(
    const float* __restrict__ W1, const float* __restrict__ b1,
    const float* __restrict__ z, const float* __restrict__ rl0,
    unsigned short* __restrict__ znb, int n_rows)
{
    const int lane = threadIdx.x & 63;
    const int wv   = threadIdx.x >> 6;
    const int rr   = blockIdx.x * 4 + wv;
    if (rr >= 2 * n_rows) return;
    const int side = rr >= n_rows;
    const int n    = rr - side * n_rows;
    const int c    = lane & 15;

    const float4 xv = (n == 0) ? ((const float4*)(rl0 + side * 64))[c]
                               : ((const float4*)(z + (size_t)rr * 64))[c];
    const float xa[4] = {xv.x, xv.y, xv.z, xv.w};

    const float zv = proj_row4(xa, W1, b1, lane);
    const float nrm = fmaxf(sqrtf(g16sum(zv * zv)), EPS);
    znb[(size_t)rr * 64 + lane] = f2bf(zv / nrm);
}

// ---- K2/K4: 3 routing iterations, one block per side (grid = 2) ----
__global__ __launch_bounds__(1024) void kroute3(
    const unsigned short* __restrict__ znb,
    float* __restrict__ rl_out,           // K2: plain write dst (rl0)
    float* __restrict__ rl1,              // K4: atomic dst
    int* __restrict__ ticket, float* __restrict__ out,
    int n_neigh, int is_last)
{
    const int n_rows = n_neigh + 1;
    const int tid  = threadIdx.x;
    const int lane = tid & 63;
    const int wv   = tid >> 6;
    const int side = blockIdx.x;
    const unsigned short* __restrict__ zb = znb + (size_t)side * n_rows * 64;

    const int j    = lane & 7;    // elem octet within row
    const int rg   = tid >> 3;    // row-group within block [0,128)
    const int base = lane & 56;   // 8-lane group start
    const int k    = j >> 1;      // channel

    __shared__ float red[16][64];
    __shared__ float sEgo[64];
    __shared__ float sRouted[64];

    if (tid < 64) sEgo[tid] = bf2f(zb[tid]);   // zn row 0 (already normalized)
    __syncthreads();

    for (int t = 0; t < 3; ++t) {
        float ego[8];
#pragma unroll
        for (int m = 0; m < 8; ++m) ego[m] = sEgo[j * 8 + m];

        float a8[8] = {0.f, 0.f, 0.f, 0.f, 0.f, 0.f, 0.f, 0.f};
        if (rg < n_neigh) {
            uint4 q = *(const uint4*)(zb + (((size_t)rg + 1) << 6) + (j << 3));
            for (int r = rg; r < n_neigh; r += 128) {
                const int rn = r + 128;
                uint4 qn = q;
                if (rn < n_neigh)
                    qn = *(const uint4*)(zb + (((size_t)rn + 1) << 6) + (j << 3));
                float x[8];
                x[0] = bflo(q.x); x[1] = bfhi(q.x);
                x[2] = bflo(q.y); x[3] = bfhi(q.y);
                x[4] = bflo(q.z); x[5] = bfhi(q.z);
                x[6] = bflo(q.w); x[7] = bfhi(q.w);
                float partial = 0.f;
#pragma unroll
                for (int m = 0; m < 8; ++m) partial = fmaf(x[m], ego[m], partial);
                const float dp = partial + __shfl_xor(partial, 1, 64);
                const float d0 = __shfl(dp, base + 0, 64);
                const float d1 = __shfl(dp, base + 2, 64);
                const float d2 = __shfl(dp, base + 4, 64);
                const float d3 = __shfl(dp, base + 6, 64);
                // dots in [-1,1] (unit vectors): no max-shift needed
                const float e0 = __expf(d0), e1 = __expf(d1);
                const float e2 = __expf(d2), e3 = __expf(d3);
                const float den = e0 + e1 + e2 + e3;
                const float eo = (k == 0) ? e0 : (k == 1) ? e1 : (k == 2) ? e2 : e3;
                const float p = eo / den;
#pragma unroll
                for (int m = 0; m < 8; ++m) a8[m] = fmaf(p, x[m], a8[m]);
                q = qn;
            }
        }
        // reduce the 8 row-groups within the wave (lanes j, j+8, ..., j+56)
#pragma unroll
        for (int mask = 8; mask <= 32; mask <<= 1)
#pragma unroll
            for (int m = 0; m < 8; ++m) a8[m] += __shfl_xor(a8[m], mask, 64);
        if (lane < 8) {
#pragma unroll
            for (int m = 0; m < 8; ++m) red[wv][lane * 8 + m] = a8[m];
        }
        __syncthreads();
        if (wv == 0) {
            float s = 0.f;
#pragma unroll
            for (int w = 0; w < 16; ++w) s += red[w][lane];
            sRouted[lane] = s;
            const float nrm = fmaxf(sqrtf(g16sum(s * s)), EPS);
            sEgo[lane] = s / nrm;
        }
        __syncthreads();
    }

    if (!is_last) {
        if (tid < 64) rl_out[side * 64 + tid] = sRouted[tid];
    } else if (wv == 0) {
        atomicAdd(&rl1[side * 64 + lane], sRouted[lane]);  // memory-side write
        __threadfence();
        int tkv = 0;
        if (lane == 0) tkv = atomicAdd(ticket, 1);
        tkv = __shfl(tkv, 0, 64);
        if (tkv == 1) {  // last block: both sides' adds are at memory-side
            const float u = atomicAdd(&rl1[0 * 64 + lane], 0.f);   // RMW read
            const float v = atomicAdd(&rl1[1 * 64 + lane], 0.f);
            out[1 + lane]  = u;
            out[65 + lane] = v;
            float p = u * v;
#pragma unroll
            for (int s = 32; s >= 1; s >>= 1) p += __shfl_xor(p, s, 64);
            if (lane == 0) out[0] = p;
        }
    }
}

extern "C" void kernel_launch(void* const* d_in, const int* in_sizes, int n_in,
                              void* d_out, int out_size, void* d_ws, size_t ws_size,
                              hipStream_t stream) {
    const int*   user       = (const int*)d_in[0];
    const int*   item       = (const int*)d_in[1];
    const int*   neigh_user = (const int*)d_in[2];
    const int*   neigh_item = (const int*)d_in[3];
    const float* Gu         = (const float*)d_in[4];
    const float* Gi         = (const float*)d_in[5];
    const float* W0         = (const float*)d_in[6];
    const float* b0         = (const float*)d_in[7];
    const float* W1         = (const float*)d_in[8];
    const float* b1         = (const float*)d_in[9];
    float* out = (float*)d_out;

    const int n_neigh = in_sizes[2];
    const int n_rows  = n_neigh + 1;

    float*          z      = (float*)d_ws;
    float*          rl0    = z + (size_t)2 * n_rows * 64;
    float*          rl1    = rl0 + 128;
    int*            ticket = (int*)(rl1 + 128);
    unsigned short* znb    = (unsigned short*)(ticket + 4);

    const dim3 pg((2 * n_rows + 3) / 4), pb(256);

    hipLaunchKernelGGL(k1_gather_proj, pg, pb, 0, stream,
                       user, item, neigh_user, neigh_item, Gu, Gi, W0, b0,
                       z, znb, rl1, ticket, n_rows);
    hipLaunchKernelGGL(kroute3, dim3(2), dim3(1024), 0, stream,
                       znb, rl0, rl1, ticket, out, n_neigh, 0);
    hipLaunchKernelGGL(k3_proj, pg, pb, 0, stream,
                       W1, b1, z, rl0, znb, n_rows);
    hipLaunchKernelGGL(kroute3, dim3(2), dim3(1024), 0, stream,
                       znb, rl0, rl1, ticket, out, n_neigh, 1);
}

// Round 9
// 103.577 us; speedup vs baseline: 2.0442x; 1.0497x over previous
//
#include <hip/hip_runtime.h>
#include <hip/hip_bf16.h>

// DisenGCN forward — 3-dispatch chain:
//   K1: gather + proj(L0) -> zb (bf16 raw), znbA (bf16 normalized); zero rl1/ticket
//   K2: blocks 0,1  = route x3 (L0) on znbA -> rl0 (plain f32)
//       blocks 2..  = proj(L1) neighbor rows: zb -> znbB          [same dispatch!]
//   K3: stage W1 in LDS; wave0 projects row0 from rl0 -> ego; route x3 (L1)
//       on znbB; ticket-fused finalize -> out
//
// Cross-kernel handoffs ride dispatch boundaries. Intra-K3 cross-block (2
// blocks): atomicAdd writes + atomicAdd(p,0) RMW reads + ticket (verified).
//
// Route layout: 8 lanes/row; lane j=lane&7 holds elems [8j..8j+7]; channel
// k=j>>1. Proj layout: lane chunk c=lane&15 holds input elems 4c..4c+3
// (replicated over four 16-lane groups); output elem m=k*16+d in lane m.
//
// ws: zb[2*n_rows*64 bf16] | znbA[...] | znbB[...] | rl0[128 f32] | rl1[128] | ticket

#define EPS 1e-12f

__device__ __forceinline__ float g16sum(float v) {
    v += __shfl_xor(v, 1, 64);
    v += __shfl_xor(v, 2, 64);
    v += __shfl_xor(v, 4, 64);
    v += __shfl_xor(v, 8, 64);
    return v;
}
__device__ __forceinline__ unsigned short f2bf(float f) {  // RNE
    unsigned int b = __float_as_uint(f);
    b += 0x7fffu + ((b >> 16) & 1u);
    return (unsigned short)(b >> 16);
}
__device__ __forceinline__ float bf2f(unsigned short u) {
    return __uint_as_float(((unsigned int)u) << 16);
}
__device__ __forceinline__ float bflo(unsigned int w) {
    return __uint_as_float(w << 16);
}
__device__ __forceinline__ float bfhi(unsigned int w) {
    return __uint_as_float(w & 0xffff0000u);
}

__device__ __forceinline__ float proj_row4(const float xa[4],
                                           const float* __restrict__ W,
                                           const float* __restrict__ b, int lane) {
    const int k = lane >> 4, d = lane & 15;
    float sum = b[k * 16 + d];
    const float* __restrict__ Wp = W + k * 1024 + d;  // W[k][i][d]
#pragma unroll
    for (int i = 0; i < 64; ++i)
        sum = fmaf(__shfl(xa[i & 3], i >> 2, 64), Wp[i * 16], sum);
    return fmaxf(sum, 0.f);
}

// 3 routing iterations over rows 1..n_neigh of zb (bf16 rows). sEgo must hold
// the normalized t=0 ego on entry. On exit sRouted = raw routed result.
__device__ __forceinline__ void route3_body(
    const unsigned short* __restrict__ zb,
    float (&red)[16][64], float* __restrict__ sEgo, float* __restrict__ sRouted,
    int tid, int lane, int wv, int n_neigh)
{
    const int j    = lane & 7;
    const int rg   = tid >> 3;
    const int base = lane & 56;
    const int k    = j >> 1;

    for (int t = 0; t < 3; ++t) {
        float ego[8];
#pragma unroll
        for (int m = 0; m < 8; ++m) ego[m] = sEgo[j * 8 + m];

        float a8[8] = {0.f, 0.f, 0.f, 0.f, 0.f, 0.f, 0.f, 0.f};
        if (rg < n_neigh) {
            uint4 q = *(const uint4*)(zb + (((size_t)rg + 1) << 6) + (j << 3));
            for (int r = rg; r < n_neigh; r += 128) {
                const int rn = r + 128;
                uint4 qn = q;
                if (rn < n_neigh)
                    qn = *(const uint4*)(zb + (((size_t)rn + 1) << 6) + (j << 3));
                float x[8];
                x[0] = bflo(q.x); x[1] = bfhi(q.x);
                x[2] = bflo(q.y); x[3] = bfhi(q.y);
                x[4] = bflo(q.z); x[5] = bfhi(q.z);
                x[6] = bflo(q.w); x[7] = bfhi(q.w);
                float partial = 0.f;
#pragma unroll
                for (int m = 0; m < 8; ++m) partial = fmaf(x[m], ego[m], partial);
                const float dp = partial + __shfl_xor(partial, 1, 64);
                const float d0 = __shfl(dp, base + 0, 64);
                const float d1 = __shfl(dp, base + 2, 64);
                const float d2 = __shfl(dp, base + 4, 64);
                const float d3 = __shfl(dp, base + 6, 64);
                const float e0 = __expf(d0), e1 = __expf(d1);
                const float e2 = __expf(d2), e3 = __expf(d3);
                const float den = e0 + e1 + e2 + e3;
                const float eo = (k == 0) ? e0 : (k == 1) ? e1 : (k == 2) ? e2 : e3;
                const float p = eo / den;
#pragma unroll
                for (int m = 0; m < 8; ++m) a8[m] = fmaf(p, x[m], a8[m]);
                q = qn;
            }
        }
#pragma unroll
        for (int mask = 8; mask <= 32; mask <<= 1)
#pragma unroll
            for (int m = 0; m < 8; ++m) a8[m] += __shfl_xor(a8[m], mask, 64);
        if (lane < 8) {
#pragma unroll
            for (int m = 0; m < 8; ++m) red[wv][lane * 8 + m] = a8[m];
        }
        __syncthreads();
        if (wv == 0) {
            float s = 0.f;
#pragma unroll
            for (int w = 0; w < 16; ++w) s += red[w][lane];
            sRouted[lane] = s;
            sEgo[lane] = s / fmaxf(sqrtf(g16sum(s * s)), EPS);
        }
        __syncthreads();
    }
}

// ---- K1: gather + proj L0 (1 row/wave); zero rl1 + ticket ----
__global__ __launch_bounds__(256) void k1_gather_proj(
    const int* __restrict__ user, const int* __restrict__ item,
    const int* __restrict__ nu, const int* __restrict__ ni,
    const float* __restrict__ Gu, const float* __restrict__ Gi,
    const float* __restrict__ W0, const float* __restrict__ b0,
    unsigned short* __restrict__ zb, unsigned short* __restrict__ znbA,
    float* __restrict__ rl1, int* __restrict__ ticket, int n_rows)
{
    if (blockIdx.x == 0) {
        if (threadIdx.x < 128) rl1[threadIdx.x] = 0.f;
        if (threadIdx.x == 0) *ticket = 0;
    }
    const int lane = threadIdx.x & 63;
    const int wv   = threadIdx.x >> 6;
    const int rr   = blockIdx.x * 4 + wv;
    if (rr >= 2 * n_rows) return;
    const int side = rr >= n_rows;
    const int n    = rr - side * n_rows;
    const int c    = lane & 15;

    int idx; const float* G;
    if (n == 0) { idx = side ? item[0] : user[0];     G = side ? Gi : Gu; }
    else        { idx = side ? ni[n - 1] : nu[n - 1]; G = side ? Gu : Gi; }
    const float4 xv = ((const float4*)(G + (size_t)idx * 64))[c];
    const float xa[4] = {xv.x, xv.y, xv.z, xv.w};

    const float zv = proj_row4(xa, W0, b0, lane);
    zb[(size_t)rr * 64 + lane] = f2bf(zv);
    const float nrm = fmaxf(sqrtf(g16sum(zv * zv)), EPS);
    znbA[(size_t)rr * 64 + lane] = f2bf(zv / nrm);
}

// ---- K2: route3(L0) on blocks 0,1  ||  proj(L1) neighbors on blocks 2.. ----
__global__ __launch_bounds__(1024) void k2_route_par_proj(
    const unsigned short* __restrict__ znbA, const unsigned short* __restrict__ zb,
    const float* __restrict__ W1, const float* __restrict__ b1,
    unsigned short* __restrict__ znbB, float* __restrict__ rl0, int n_neigh)
{
    const int n_rows = n_neigh + 1;
    const int tid  = threadIdx.x;
    const int lane = tid & 63;
    const int wv   = tid >> 6;

    if (blockIdx.x < 2) {
        const int side = blockIdx.x;
        const unsigned short* __restrict__ za = znbA + (size_t)side * n_rows * 64;
        __shared__ float red[16][64];
        __shared__ float sEgo[64];
        __shared__ float sRouted[64];
        if (tid < 64) sEgo[tid] = bf2f(za[tid]);  // normalized row 0
        __syncthreads();
        route3_body(za, red, sEgo, sRouted, tid, lane, wv, n_neigh);
        if (tid < 64) rl0[side * 64 + tid] = sRouted[tid];
        return;
    }

    // proj L1 for neighbor rows (1 row/wave, 16 rows/block)
    const int rr2 = (blockIdx.x - 2) * 16 + wv;   // [0, 2*n_neigh)
    if (rr2 >= 2 * n_neigh) return;
    const int side = rr2 >= n_neigh;
    const int n    = rr2 - side * n_neigh + 1;
    const size_t row = (size_t)side * n_rows + n;
    const int c    = lane & 15;

    const ushort4 uv = ((const ushort4*)(zb + row * 64))[c];
    const float xa[4] = {bf2f(uv.x), bf2f(uv.y), bf2f(uv.z), bf2f(uv.w)};
    const float zv = proj_row4(xa, W1, b1, lane);
    const float nrm = fmaxf(sqrtf(g16sum(zv * zv)), EPS);
    znbB[row * 64 + lane] = f2bf(zv / nrm);
}

// ---- K3: row0 proj (from rl0) + route3(L1) + finalize ----
__global__ __launch_bounds__(1024) void k3_route_final(
    const unsigned short* __restrict__ znbB,
    const float* __restrict__ W1, const float* __restrict__ b1,
    const float* __restrict__ rl0, float* __restrict__ rl1,
    int* __restrict__ ticket, float* __restrict__ out, int n_neigh)
{
    const int n_rows = n_neigh + 1;
    const int tid  = threadIdx.x;
    const int lane = tid & 63;
    const int wv   = tid >> 6;
    const int side = blockIdx.x;
    const unsigned short* __restrict__ zbB = znbB + (size_t)side * n_rows * 64;

    __shared__ float sW[4096];   // i-major: sW[i*64 + m]
    __shared__ float red[16][64];
    __shared__ float sEgo[64];
    __shared__ float sRouted[64];

    for (int q = tid; q < 4096; q += 1024) {
        const int i = q >> 6, m = q & 63;
        sW[q] = W1[(m >> 4) * 1024 + i * 16 + (m & 15)];
    }
    __syncthreads();

    if (wv == 0) {  // row-0 proj: input = rl0 (raw routed L0), dispatch-boundary read
        const float x = rl0[side * 64 + lane];
        float xa[4];
#pragma unroll
        for (int jj = 0; jj < 4; ++jj) xa[jj] = __shfl(x, (lane & 15) * 4 + jj, 64);
        float sum = b1[lane];
#pragma unroll
        for (int i = 0; i < 64; ++i)
            sum = fmaf(__shfl(xa[i & 3], i >> 2, 64), sW[i * 64 + lane], sum);
        sum = fmaxf(sum, 0.f);
        sEgo[lane] = sum / fmaxf(sqrtf(g16sum(sum * sum)), EPS);
    }
    __syncthreads();

    route3_body(zbB, red, sEgo, sRouted, tid, lane, wv, n_neigh);

    if (wv == 0) {
        atomicAdd(&rl1[side * 64 + lane], sRouted[lane]);  // memory-side write
        __threadfence();
        int tkv = 0;
        if (lane == 0) tkv = atomicAdd(ticket, 1);
        tkv = __shfl(tkv, 0, 64);
        if (tkv == 1) {
            const float u = atomicAdd(&rl1[0 * 64 + lane], 0.f);  // RMW reads
            const float v = atomicAdd(&rl1[1 * 64 + lane], 0.f);
            out[1 + lane]  = u;
            out[65 + lane] = v;
            float p = u * v;
#pragma unroll
            for (int s = 32; s >= 1; s >>= 1) p += __shfl_xor(p, s, 64);
            if (lane == 0) out[0] = p;
        }
    }
}

extern "C" void kernel_launch(void* const* d_in, const int* in_sizes, int n_in,
                              void* d_out, int out_size, void* d_ws, size_t ws_size,
                              hipStream_t stream) {
    const int*   user       = (const int*)d_in[0];
    const int*   item       = (const int*)d_in[1];
    const int*   neigh_user = (const int*)d_in[2];
    const int*   neigh_item = (const int*)d_in[3];
    const float* Gu         = (const float*)d_in[4];
    const float* Gi         = (const float*)d_in[5];
    const float* W0         = (const float*)d_in[6];
    const float* b0         = (const float*)d_in[7];
    const float* W1         = (const float*)d_in[8];
    const float* b1         = (const float*)d_in[9];
    float* out = (float*)d_out;

    const int n_neigh = in_sizes[2];
    const int n_rows  = n_neigh + 1;
    const size_t rowsz = (size_t)2 * n_rows * 64;

    unsigned short* zb   = (unsigned short*)d_ws;
    unsigned short* znbA = zb + rowsz;
    unsigned short* znbB = znbA + rowsz;
    float*          rl0  = (float*)(znbB + rowsz);
    float*          rl1  = rl0 + 128;
    int*            ticket = (int*)(rl1 + 128);

    hipLaunchKernelGGL(k1_gather_proj, dim3((2 * n_rows + 3) / 4), dim3(256), 0, stream,
                       user, item, neigh_user, neigh_item, Gu, Gi, W0, b0,
                       zb, znbA, rl1, ticket, n_rows);
    hipLaunchKernelGGL(k2_route_par_proj, dim3(2 + (2 * n_neigh + 15) / 16), dim3(1024),
                       0, stream, znbA, zb, W1, b1, znbB, rl0, n_neigh);
    hipLaunchKernelGGL(k3_route_final, dim3(2), dim3(1024), 0, stream,
                       znbB, W1, b1, rl0, rl1, ticket, out, n_neigh);
}

// Round 10
// 91.468 us; speedup vs baseline: 2.3148x; 1.1324x over previous
//
#include <hip/hip_runtime.h>
#include <hip/hip_bf16.h>

// DisenGCN forward — 2-dispatch chain:
//   K1 (chip-wide): gather -> z0=proj(W0) -> znbA=norm(z0) [bf16]
//                   and (neighbors only) z1=proj(W1,z0) -> znbB=norm(z1) [bf16]
//                   (valid because routing only ever replaces ROW 0 between
//                    layers; neighbor rows' L1 input is plain z0). zero rl1/ticket.
//   K2 (2 blocks x 1024): route3(L0) on znbA -> rl0 (in-block!) -> row0 proj(W1)
//                   -> ego -> route3(L1) on znbB -> out + ticket-fused xui.
//
// Cross-kernel handoff rides the dispatch boundary. The only cross-block
// exchange (final xui dot between the 2 K2 blocks) uses atomicAdd writes +
// atomicAdd(p,0) RMW reads + ticket (R4/R8/R9-verified safe across XCDs).
//
// Route layout: 8 lanes/row; lane j=lane&7 holds elems [8j..8j+7] (uint4 of
// 8 bf16); channel k=j>>1. Proj layout: lane chunk c=lane&15 holds input elems
// 4c..4c+3 (replicated over four 16-lane groups); output elem m=k*16+d in lane m.
// Ego in sEgo is normalized AND pre-scaled by log2(e) so softmax uses exp2.
//
// ws: znbA[2*n_rows*64 bf16] | znbB[same] | rl1[128 f32] | ticket(int)

#define EPS 1e-12f
#define LOG2E 1.44269504088896f

__device__ __forceinline__ float g16sum(float v) {
    v += __shfl_xor(v, 1, 64);
    v += __shfl_xor(v, 2, 64);
    v += __shfl_xor(v, 4, 64);
    v += __shfl_xor(v, 8, 64);
    return v;
}
__device__ __forceinline__ unsigned short f2bf(float f) {  // RNE
    unsigned int b = __float_as_uint(f);
    b += 0x7fffu + ((b >> 16) & 1u);
    return (unsigned short)(b >> 16);
}
__device__ __forceinline__ float bflo(unsigned int w) {
    return __uint_as_float(w << 16);
}
__device__ __forceinline__ float bfhi(unsigned int w) {
    return __uint_as_float(w & 0xffff0000u);
}

__device__ __forceinline__ float proj_row4(const float xa[4],
                                           const float* __restrict__ W,
                                           const float* __restrict__ b, int lane) {
    const int k = lane >> 4, d = lane & 15;
    float sum = b[k * 16 + d];
    const float* __restrict__ Wp = W + k * 1024 + d;  // W[k][i][d]
#pragma unroll
    for (int i = 0; i < 64; ++i)
        sum = fmaf(__shfl(xa[i & 3], i >> 2, 64), Wp[i * 16], sum);
    return fmaxf(sum, 0.f);
}

// 3 routing iterations over rows 1..n_neigh. sEgo: normalized ego * LOG2E on
// entry; maintained across iterations. On exit sRouted = raw routed result.
__device__ __forceinline__ void route3_body(
    const unsigned short* __restrict__ zb,
    float (&red)[16][64], float* __restrict__ sEgo, float* __restrict__ sRouted,
    int tid, int lane, int wv, int n_neigh)
{
    const int j    = lane & 7;
    const int rg   = tid >> 3;
    const int base = lane & 56;

    for (int t = 0; t < 3; ++t) {
        float ego[8];
#pragma unroll
        for (int m = 0; m < 8; ++m) ego[m] = sEgo[j * 8 + m];

        float a8[8] = {0.f, 0.f, 0.f, 0.f, 0.f, 0.f, 0.f, 0.f};
        if (rg < n_neigh) {
            uint4 q = *(const uint4*)(zb + (((size_t)rg + 1) << 6) + (j << 3));
            for (int r = rg; r < n_neigh; r += 128) {
                const int rn = r + 128;
                uint4 qn = q;
                if (rn < n_neigh)
                    qn = *(const uint4*)(zb + (((size_t)rn + 1) << 6) + (j << 3));
                float x[8];
                x[0] = bflo(q.x); x[1] = bfhi(q.x);
                x[2] = bflo(q.y); x[3] = bfhi(q.y);
                x[4] = bflo(q.z); x[5] = bfhi(q.z);
                x[6] = bflo(q.w); x[7] = bfhi(q.w);
                float partial = 0.f;
#pragma unroll
                for (int m = 0; m < 8; ++m) partial = fmaf(x[m], ego[m], partial);
                const float dp = partial + __shfl_xor(partial, 1, 64);  // my channel's dot*log2e
                const float eo = exp2f(dp);
                const float den = __shfl(eo, base + 0, 64) + __shfl(eo, base + 2, 64)
                                + __shfl(eo, base + 4, 64) + __shfl(eo, base + 6, 64);
                const float p = eo * __builtin_amdgcn_rcpf(den);
#pragma unroll
                for (int m = 0; m < 8; ++m) a8[m] = fmaf(p, x[m], a8[m]);
                q = qn;
            }
        }
#pragma unroll
        for (int mask = 8; mask <= 32; mask <<= 1)
#pragma unroll
            for (int m = 0; m < 8; ++m) a8[m] += __shfl_xor(a8[m], mask, 64);
        if (lane < 8) {
#pragma unroll
            for (int m = 0; m < 8; ++m) red[wv][lane * 8 + m] = a8[m];
        }
        __syncthreads();
        if (wv == 0) {
            float s = 0.f;
#pragma unroll
            for (int w = 0; w < 16; ++w) s += red[w][lane];
            sRouted[lane] = s;
            sEgo[lane] = (s / fmaxf(sqrtf(g16sum(s * s)), EPS)) * LOG2E;
        }
        __syncthreads();
    }
}

// ---- K1: gather + proj L0 + (neighbors) proj L1; zero rl1 + ticket ----
__global__ __launch_bounds__(256) void k1_gather_proj2(
    const int* __restrict__ user, const int* __restrict__ item,
    const int* __restrict__ nu, const int* __restrict__ ni,
    const float* __restrict__ Gu, const float* __restrict__ Gi,
    const float* __restrict__ W0, const float* __restrict__ b0,
    const float* __restrict__ W1, const float* __restrict__ b1,
    unsigned short* __restrict__ znbA, unsigned short* __restrict__ znbB,
    float* __restrict__ rl1, int* __restrict__ ticket, int n_rows)
{
    if (blockIdx.x == 0) {
        if (threadIdx.x < 128) rl1[threadIdx.x] = 0.f;
        if (threadIdx.x == 0) *ticket = 0;
    }
    const int lane = threadIdx.x & 63;
    const int wv   = threadIdx.x >> 6;
    const int rr   = blockIdx.x * 4 + wv;
    if (rr >= 2 * n_rows) return;
    const int side = rr >= n_rows;
    const int n    = rr - side * n_rows;
    const int c    = lane & 15;

    int idx; const float* G;
    if (n == 0) { idx = side ? item[0] : user[0];     G = side ? Gi : Gu; }
    else        { idx = side ? ni[n - 1] : nu[n - 1]; G = side ? Gu : Gi; }
    const float4 xv = ((const float4*)(G + (size_t)idx * 64))[c];
    const float xa[4] = {xv.x, xv.y, xv.z, xv.w};

    // layer-0 projection (lane m holds elem m)
    const float z0 = proj_row4(xa, W0, b0, lane);
    const float nrm0 = fmaxf(sqrtf(g16sum(z0 * z0)), EPS);
    znbA[(size_t)rr * 64 + lane] = f2bf(z0 / nrm0);

    if (n == 0) return;  // row 0's L1 input is the routed result (K2 in-block)

    // layer-1 projection of z0 (neighbors only): regroup to chunk layout
    float xa2[4];
#pragma unroll
    for (int jj = 0; jj < 4; ++jj) xa2[jj] = __shfl(z0, (c << 2) | jj, 64);
    const float z1 = proj_row4(xa2, W1, b1, lane);
    const float nrm1 = fmaxf(sqrtf(g16sum(z1 * z1)), EPS);
    znbB[(size_t)rr * 64 + lane] = f2bf(z1 / nrm1);
}

// ---- K2: route3(L0) + row0 proj(W1) + route3(L1) + finalize (grid = 2) ----
__global__ __launch_bounds__(1024) void k2_route_all(
    const unsigned short* __restrict__ znbA, const unsigned short* __restrict__ znbB,
    const float* __restrict__ W1, const float* __restrict__ b1,
    float* __restrict__ rl1, int* __restrict__ ticket,
    float* __restrict__ out, int n_neigh)
{
    const int n_rows = n_neigh + 1;
    const int tid  = threadIdx.x;
    const int lane = tid & 63;
    const int wv   = tid >> 6;
    const int side = blockIdx.x;
    const unsigned short* __restrict__ zA = znbA + (size_t)side * n_rows * 64;
    const unsigned short* __restrict__ zB = znbB + (size_t)side * n_rows * 64;

    __shared__ float sW[4096];   // W1 i-major: sW[i*64 + m]
    __shared__ float red[16][64];
    __shared__ float sEgo[64];
    __shared__ float sRouted[64];

    for (int q = tid; q < 4096; q += 1024) {
        const int i = q >> 6, m = q & 63;
        sW[q] = W1[(m >> 4) * 1024 + i * 16 + (m & 15)];
    }
    if (tid < 64) {
        const unsigned short u = zA[tid];        // normalized row 0
        sEgo[tid] = __uint_as_float(((unsigned int)u) << 16) * LOG2E;
    }
    __syncthreads();

    // ---- layer-0 routing ----
    route3_body(zA, red, sEgo, sRouted, tid, lane, wv, n_neigh);

    // ---- row-0 layer-1 projection from routed L0 (in-block!) ----
    if (wv == 0) {
        float xa[4];
#pragma unroll
        for (int jj = 0; jj < 4; ++jj) xa[jj] = sRouted[((lane & 15) << 2) | jj];
        float sum = b1[lane];
#pragma unroll
        for (int i = 0; i < 64; ++i)
            sum = fmaf(__shfl(xa[i & 3], i >> 2, 64), sW[i * 64 + lane], sum);
        sum = fmaxf(sum, 0.f);
        sEgo[lane] = (sum / fmaxf(sqrtf(g16sum(sum * sum)), EPS)) * LOG2E;
    }
    __syncthreads();

    // ---- layer-1 routing ----
    route3_body(zB, red, sEgo, sRouted, tid, lane, wv, n_neigh);

    // ---- outputs ----
    if (wv == 0) {
        out[1 + side * 64 + lane] = sRouted[lane];           // eu0 / ei0 (own side)
        atomicAdd(&rl1[side * 64 + lane], sRouted[lane]);    // memory-side write
        __threadfence();
        int tkv = 0;
        if (lane == 0) tkv = atomicAdd(ticket, 1);
        tkv = __shfl(tkv, 0, 64);
        if (tkv == 1) {                                      // last of the 2 blocks
            const float u = atomicAdd(&rl1[0 * 64 + lane], 0.f);  // RMW reads
            const float v = atomicAdd(&rl1[1 * 64 + lane], 0.f);
            float p = u * v;
#pragma unroll
            for (int s = 32; s >= 1; s >>= 1) p += __shfl_xor(p, s, 64);
            if (lane == 0) out[0] = p;
        }
    }
}

extern "C" void kernel_launch(void* const* d_in, const int* in_sizes, int n_in,
                              void* d_out, int out_size, void* d_ws, size_t ws_size,
                              hipStream_t stream) {
    const int*   user       = (const int*)d_in[0];
    const int*   item       = (const int*)d_in[1];
    const int*   neigh_user = (const int*)d_in[2];
    const int*   neigh_item = (const int*)d_in[3];
    const float* Gu         = (const float*)d_in[4];
    const float* Gi         = (const float*)d_in[5];
    const float* W0         = (const float*)d_in[6];
    const float* b0         = (const float*)d_in[7];
    const float* W1         = (const float*)d_in[8];
    const float* b1         = (const float*)d_in[9];
    float* out = (float*)d_out;

    const int n_neigh = in_sizes[2];
    const int n_rows  = n_neigh + 1;
    const size_t rowsz = (size_t)2 * n_rows * 64;

    unsigned short* znbA = (unsigned short*)d_ws;
    unsigned short* znbB = znbA + rowsz;
    float*          rl1  = (float*)(znbB + rowsz);
    int*            ticket = (int*)(rl1 + 128);

    hipLaunchKernelGGL(k1_gather_proj2, dim3((2 * n_rows + 3) / 4), dim3(256), 0, stream,
                       user, item, neigh_user, neigh_item, Gu, Gi, W0, b0, W1, b1,
                       znbA, znbB, rl1, ticket, n_rows);
    hipLaunchKernelGGL(k2_route_all, dim3(2), dim3(1024), 0, stream,
                       znbA, znbB, W1, b1, rl1, ticket, out, n_neigh);
}

// Round 12
// 55.406 us; speedup vs baseline: 3.8213x; 1.6509x over previous
//
#include <hip/hip_runtime.h>
#include <hip/hip_bf16.h>

// DisenGCN forward — 2-dispatch chain, multi-block routing (replay-safe):
//   K1 (chip-wide): gather -> z0=proj(W0) -> znbA [bf16 norm]; neighbors also
//                   z1=proj(W1,z0) -> znbB [bf16 norm]. Zeroes ticks (13 ints).
//   K2 (8 blocks = 4/side x 1024 thr): 6 routing sweeps; per sweep each block
//       writes its partial into its OWN slot via atomicExch (overwrite ->
//       replay-idempotent, no pre-zero needed), fence+ticket, RMW-poll (==SPB),
//       RMW-read + sum the SPB partials -> new ego. s==2: row-0 proj(W1).
//       Finalize via cross-side ticket + RMW reads.
//
// Cross-block data rules (R4/R8/R9-verified): atomic writes (add/exch,
// memory-side) + atomicAdd(p,0) RMW reads + tickets. Plain loads cross blocks
// only over dispatch boundaries (znbA/znbB).
//
// Route layout: 8 lanes/row; lane j=lane&7 holds elems [8j..8j+7]; channel
// k=j>>1. Ego in sEgo normalized AND pre-scaled by log2(e) (exp2 softmax).
//
// ws: znbA[2*n_rows*64 bf16] | znbB[same] | acc[6*2*SPB*64 f32] | ticks[13 int]

#define EPS 1e-12f
#define LOG2E 1.44269504088896f
#define SPB 4              // blocks per side in K2
#define NBK (2 * SPB)

__device__ __forceinline__ float g16sum(float v) {
    v += __shfl_xor(v, 1, 64);
    v += __shfl_xor(v, 2, 64);
    v += __shfl_xor(v, 4, 64);
    v += __shfl_xor(v, 8, 64);
    return v;
}
__device__ __forceinline__ unsigned short f2bf(float f) {  // RNE
    unsigned int b = __float_as_uint(f);
    b += 0x7fffu + ((b >> 16) & 1u);
    return (unsigned short)(b >> 16);
}
__device__ __forceinline__ float bf2f(unsigned short u) {
    return __uint_as_float(((unsigned int)u) << 16);
}
__device__ __forceinline__ float bflo(unsigned int w) {
    return __uint_as_float(w << 16);
}
__device__ __forceinline__ float bfhi(unsigned int w) {
    return __uint_as_float(w & 0xffff0000u);
}
__device__ __forceinline__ float rmwf(float* p) { return atomicAdd(p, 0.f); }

__device__ __forceinline__ float proj_row4(const float xa[4],
                                           const float* __restrict__ W,
                                           const float* __restrict__ b, int lane) {
    const int k = lane >> 4, d = lane & 15;
    float sum = b[k * 16 + d];
    const float* __restrict__ Wp = W + k * 1024 + d;  // W[k][i][d]
#pragma unroll
    for (int i = 0; i < 64; ++i)
        sum = fmaf(__shfl(xa[i & 3], i >> 2, 64), Wp[i * 16], sum);
    return fmaxf(sum, 0.f);
}

// ---- K1: gather + proj L0 + (neighbors) proj L1; zero ticks ----
__global__ __launch_bounds__(256) void k1_gather_proj2(
    const int* __restrict__ user, const int* __restrict__ item,
    const int* __restrict__ nu, const int* __restrict__ ni,
    const float* __restrict__ Gu, const float* __restrict__ Gi,
    const float* __restrict__ W0, const float* __restrict__ b0,
    const float* __restrict__ W1, const float* __restrict__ b1,
    unsigned short* __restrict__ znbA, unsigned short* __restrict__ znbB,
    int* __restrict__ ticks, int n_rows)
{
    if (blockIdx.x == 0 && threadIdx.x < 13) ticks[threadIdx.x] = 0;

    const int lane = threadIdx.x & 63;
    const int wv   = threadIdx.x >> 6;
    const int rr   = blockIdx.x * 4 + wv;
    if (rr >= 2 * n_rows) return;
    const int side = rr >= n_rows;
    const int n    = rr - side * n_rows;
    const int c    = lane & 15;

    int idx; const float* G;
    if (n == 0) { idx = side ? item[0] : user[0];     G = side ? Gi : Gu; }
    else        { idx = side ? ni[n - 1] : nu[n - 1]; G = side ? Gu : Gi; }
    const float4 xv = ((const float4*)(G + (size_t)idx * 64))[c];
    const float xa[4] = {xv.x, xv.y, xv.z, xv.w};

    const float z0 = proj_row4(xa, W0, b0, lane);
    const float nrm0 = fmaxf(sqrtf(g16sum(z0 * z0)), EPS);
    znbA[(size_t)rr * 64 + lane] = f2bf(z0 / nrm0);

    if (n == 0) return;  // row 0's L1 input is the routed result (K2)

    float xa2[4];
#pragma unroll
    for (int jj = 0; jj < 4; ++jj) xa2[jj] = __shfl(z0, (c << 2) | jj, 64);
    const float z1 = proj_row4(xa2, W1, b1, lane);
    const float nrm1 = fmaxf(sqrtf(g16sum(z1 * z1)), EPS);
    znbB[(size_t)rr * 64 + lane] = f2bf(z1 / nrm1);
}

// ---- K2: 6 routing sweeps across 4 blocks/side + finalize ----
__global__ __launch_bounds__(1024) void k2_route_all(
    const unsigned short* __restrict__ znbA, const unsigned short* __restrict__ znbB,
    const float* __restrict__ W1, const float* __restrict__ b1,
    float* __restrict__ acc, int* __restrict__ ticks,
    float* __restrict__ out, int n_neigh)
{
    const int n_rows = n_neigh + 1;
    const int tid  = threadIdx.x;
    const int lane = tid & 63;
    const int wv   = tid >> 6;
    const int side = blockIdx.x & 1;
    const int bg   = blockIdx.x >> 1;
    const unsigned short* __restrict__ zA = znbA + (size_t)side * n_rows * 64;
    const unsigned short* __restrict__ zB = znbB + (size_t)side * n_rows * 64;

    __shared__ float sW[4096];   // W1 i-major: sW[i*64 + m]
    __shared__ float red[16][64];
    __shared__ float sEgo[64];
    __shared__ float sTmp[64];

    for (int q = tid; q < 4096; q += 1024) {
        const int i = q >> 6, m = q & 63;
        sW[q] = W1[(m >> 4) * 1024 + i * 16 + (m & 15)];
    }
    if (tid < 64) sEgo[tid] = bf2f(zA[tid]) * LOG2E;  // normalized row 0
    __syncthreads();

    const int j   = lane & 7;
    const int rg0 = bg * 128 + (tid >> 3);   // this block's first row offset

    for (int s = 0; s < 6; ++s) {
        const unsigned short* __restrict__ zb = (s < 3) ? zA : zB;
        float ego[8];
#pragma unroll
        for (int m = 0; m < 8; ++m) ego[m] = sEgo[j * 8 + m];

        float a8[8] = {0.f, 0.f, 0.f, 0.f, 0.f, 0.f, 0.f, 0.f};
        if (rg0 < n_neigh) {
            uint4 q = *(const uint4*)(zb + (((size_t)rg0 + 1) << 6) + (j << 3));
            for (int r = rg0; r < n_neigh; r += SPB * 128) {
                const int rn = r + SPB * 128;
                uint4 qn = q;
                if (rn < n_neigh)
                    qn = *(const uint4*)(zb + (((size_t)rn + 1) << 6) + (j << 3));
                float x[8];
                x[0] = bflo(q.x); x[1] = bfhi(q.x);
                x[2] = bflo(q.y); x[3] = bfhi(q.y);
                x[4] = bflo(q.z); x[5] = bfhi(q.z);
                x[6] = bflo(q.w); x[7] = bfhi(q.w);
                float partial = 0.f;
#pragma unroll
                for (int m = 0; m < 8; ++m) partial = fmaf(x[m], ego[m], partial);
                const float dp = partial + __shfl_xor(partial, 1, 64);  // ch dot * log2e
                const float eo = exp2f(dp);
                float den = eo + __shfl_xor(eo, 2, 64);
                den += __shfl_xor(den, 4, 64);                          // all 4 channels
                const float p = eo * __builtin_amdgcn_rcpf(den);
#pragma unroll
                for (int m = 0; m < 8; ++m) a8[m] = fmaf(p, x[m], a8[m]);
                q = qn;
            }
        }
#pragma unroll
        for (int mask = 8; mask <= 32; mask <<= 1)
#pragma unroll
            for (int m = 0; m < 8; ++m) a8[m] += __shfl_xor(a8[m], mask, 64);
        if (lane < 8) {
#pragma unroll
            for (int m = 0; m < 8; ++m) red[wv][lane * 8 + m] = a8[m];
        }
        __syncthreads();

        // per-block partial -> own slot (atomicExch: overwrite, replay-safe)
        float* slotbase = acc + (size_t)(s * 2 + side) * SPB * 64;
        int* tick = &ticks[side * 6 + s];
        if (wv == 0) {
            float ssum = 0.f;
#pragma unroll
            for (int w = 0; w < 16; ++w) ssum += red[w][lane];
            atomicExch(&slotbase[bg * 64 + lane], ssum);
        }
        if (tid == 0) {
            __threadfence();                       // drain my slot write
            atomicAdd(tick, 1);
            while (atomicAdd(tick, 0) < SPB) __builtin_amdgcn_s_sleep(1);
        }
        __syncthreads();                           // release whole block

        if (s < 5) {
            if (wv == 0) {
                float e = 0.f;
#pragma unroll
                for (int bb = 0; bb < SPB; ++bb) e += rmwf(&slotbase[bb * 64 + lane]);
                if (s == 2) {
                    sTmp[lane] = e;                // raw routed L0 for row-0 proj
                } else {
                    sEgo[lane] = (e / fmaxf(sqrtf(g16sum(e * e)), EPS)) * LOG2E;
                }
            }
            __syncthreads();
            if (s == 2) {
                if (wv == 0) {
                    float xa[4];
#pragma unroll
                    for (int jj = 0; jj < 4; ++jj) xa[jj] = sTmp[((lane & 15) << 2) | jj];
                    float sum = b1[lane];
#pragma unroll
                    for (int i = 0; i < 64; ++i)
                        sum = fmaf(__shfl(xa[i & 3], i >> 2, 64), sW[i * 64 + lane], sum);
                    sum = fmaxf(sum, 0.f);
                    sEgo[lane] = (sum / fmaxf(sqrtf(g16sum(sum * sum)), EPS)) * LOG2E;
                }
                __syncthreads();
            }
        }
    }

    // ---- finalize (slot 5 partials complete for own side after its barrier) ----
    if (bg == 0 && wv == 0) {
        float* slot5 = acc + (size_t)(5 * 2 + side) * SPB * 64;
        float e = 0.f;
#pragma unroll
        for (int bb = 0; bb < SPB; ++bb) e += rmwf(&slot5[bb * 64 + lane]);
        out[1 + side * 64 + lane] = e;
        __threadfence();
        int tkv = 0;
        if (lane == 0) tkv = atomicAdd(&ticks[12], 1);
        tkv = __shfl(tkv, 0, 64);
        if (tkv == 1) {                            // both sides' out writes done
            float u = 0.f, v = 0.f;
            float* s5u = acc + (size_t)(5 * 2 + 0) * SPB * 64;
            float* s5i = acc + (size_t)(5 * 2 + 1) * SPB * 64;
#pragma unroll
            for (int bb = 0; bb < SPB; ++bb) {
                u += rmwf(&s5u[bb * 64 + lane]);
                v += rmwf(&s5i[bb * 64 + lane]);
            }
            float p = u * v;
#pragma unroll
            for (int sh = 32; sh >= 1; sh >>= 1) p += __shfl_xor(p, sh, 64);
            if (lane == 0) out[0] = p;
        }
    }
}

extern "C" void kernel_launch(void* const* d_in, const int* in_sizes, int n_in,
                              void* d_out, int out_size, void* d_ws, size_t ws_size,
                              hipStream_t stream) {
    const int*   user       = (const int*)d_in[0];
    const int*   item       = (const int*)d_in[1];
    const int*   neigh_user = (const int*)d_in[2];
    const int*   neigh_item = (const int*)d_in[3];
    const float* Gu         = (const float*)d_in[4];
    const float* Gi         = (const float*)d_in[5];
    const float* W0         = (const float*)d_in[6];
    const float* b0         = (const float*)d_in[7];
    const float* W1         = (const float*)d_in[8];
    const float* b1         = (const float*)d_in[9];
    float* out = (float*)d_out;

    const int n_neigh = in_sizes[2];
    const int n_rows  = n_neigh + 1;
    const size_t rowsz = (size_t)2 * n_rows * 64;

    unsigned short* znbA = (unsigned short*)d_ws;
    unsigned short* znbB = znbA + rowsz;
    float*          acc  = (float*)(znbB + rowsz);
    int*            ticks = (int*)(acc + 6 * 2 * SPB * 64);

    hipLaunchKernelGGL(k1_gather_proj2, dim3((2 * n_rows + 3) / 4), dim3(256), 0, stream,
                       user, item, neigh_user, neigh_item, Gu, Gi, W0, b0, W1, b1,
                       znbA, znbB, ticks, n_rows);
    hipLaunchKernelGGL(k2_route_all, dim3(NBK), dim3(1024), 0, stream,
                       znbA, znbB, W1, b1, acc, ticks, out, n_neigh);
}

// Round 13
// 49.858 us; speedup vs baseline: 4.2466x; 1.1113x over previous
//
#include <hip/hip_runtime.h>
#include <hip/hip_bf16.h>

// DisenGCN forward — 2-dispatch chain, 8-blocks/side routing, flag-based sync:
//   K1 (chip-wide): gather -> z0=proj(W0) -> znbA [bf16 norm]; neighbors also
//                   z1=proj(W1,z0) -> znbB [bf16 norm]. Zeroes flags (96 ints).
//   K2 (16 blocks = 8/side x 1024 thr): 6 routing sweeps. Per sweep:
//       block partial -> atomicExch into own slot (replay-idempotent)
//       -> wave-wide fence -> atomicExch flag[bg]=1
//       -> reader waves 0..7 poll flag[bb] (lane0) + RMW-read slot[bb] IN
//          PARALLEL -> LDS -> wv0 sums -> new ego. s==2: row-0 proj(W1).
//       s==5: block(0,0) polls all 16 flags/slots (16 waves) and finalizes.
//
// Cross-block rules (R4/R8/R9/R12-verified): atomic writes + atomicAdd(p,0)
// RMW reads + RMW flag polls. Plain loads cross blocks only at dispatch
// boundaries (znbA/znbB, flag zeroing).
//
// Route layout: 8 lanes/row; lane j=lane&7 holds elems [8j..8j+7]; channel
// k=j>>1. Ego in sEgo normalized AND pre-scaled by log2(e) (exp2 softmax).
//
// ws: znbA[2*n_rows*64 bf16] | znbB[same] | acc[6*2*SPB*64 f32] | flags[96 int]

#define EPS 1e-12f
#define LOG2E 1.44269504088896f
#define SPB 8              // blocks per side in K2
#define NBK (2 * SPB)

__device__ __forceinline__ float g16sum(float v) {
    v += __shfl_xor(v, 1, 64);
    v += __shfl_xor(v, 2, 64);
    v += __shfl_xor(v, 4, 64);
    v += __shfl_xor(v, 8, 64);
    return v;
}
__device__ __forceinline__ unsigned short f2bf(float f) {  // RNE
    unsigned int b = __float_as_uint(f);
    b += 0x7fffu + ((b >> 16) & 1u);
    return (unsigned short)(b >> 16);
}
__device__ __forceinline__ float bf2f(unsigned short u) {
    return __uint_as_float(((unsigned int)u) << 16);
}
__device__ __forceinline__ float bflo(unsigned int w) {
    return __uint_as_float(w << 16);
}
__device__ __forceinline__ float bfhi(unsigned int w) {
    return __uint_as_float(w & 0xffff0000u);
}
__device__ __forceinline__ float rmwf(float* p) { return atomicAdd(p, 0.f); }

__device__ __forceinline__ float proj_row4(const float xa[4],
                                           const float* __restrict__ W,
                                           const float* __restrict__ b, int lane) {
    const int k = lane >> 4, d = lane & 15;
    float sum = b[k * 16 + d];
    const float* __restrict__ Wp = W + k * 1024 + d;  // W[k][i][d]
#pragma unroll
    for (int i = 0; i < 64; ++i)
        sum = fmaf(__shfl(xa[i & 3], i >> 2, 64), Wp[i * 16], sum);
    return fmaxf(sum, 0.f);
}

// ---- K1: gather + proj L0 + (neighbors) proj L1; zero flags ----
__global__ __launch_bounds__(256) void k1_gather_proj2(
    const int* __restrict__ user, const int* __restrict__ item,
    const int* __restrict__ nu, const int* __restrict__ ni,
    const float* __restrict__ Gu, const float* __restrict__ Gi,
    const float* __restrict__ W0, const float* __restrict__ b0,
    const float* __restrict__ W1, const float* __restrict__ b1,
    unsigned short* __restrict__ znbA, unsigned short* __restrict__ znbB,
    int* __restrict__ flags, int n_rows)
{
    if (blockIdx.x == 0 && threadIdx.x < 6 * 2 * SPB) flags[threadIdx.x] = 0;

    const int lane = threadIdx.x & 63;
    const int wv   = threadIdx.x >> 6;
    const int rr   = blockIdx.x * 4 + wv;
    if (rr >= 2 * n_rows) return;
    const int side = rr >= n_rows;
    const int n    = rr - side * n_rows;
    const int c    = lane & 15;

    int idx; const float* G;
    if (n == 0) { idx = side ? item[0] : user[0];     G = side ? Gi : Gu; }
    else        { idx = side ? ni[n - 1] : nu[n - 1]; G = side ? Gu : Gi; }
    const float4 xv = ((const float4*)(G + (size_t)idx * 64))[c];
    const float xa[4] = {xv.x, xv.y, xv.z, xv.w};

    const float z0 = proj_row4(xa, W0, b0, lane);
    const float nrm0 = fmaxf(sqrtf(g16sum(z0 * z0)), EPS);
    znbA[(size_t)rr * 64 + lane] = f2bf(z0 / nrm0);

    if (n == 0) return;  // row 0's L1 input is the routed result (K2)

    float xa2[4];
#pragma unroll
    for (int jj = 0; jj < 4; ++jj) xa2[jj] = __shfl(z0, (c << 2) | jj, 64);
    const float z1 = proj_row4(xa2, W1, b1, lane);
    const float nrm1 = fmaxf(sqrtf(g16sum(z1 * z1)), EPS);
    znbB[(size_t)rr * 64 + lane] = f2bf(z1 / nrm1);
}

// ---- K2: 6 routing sweeps across 8 blocks/side + fused finalize ----
__global__ __launch_bounds__(1024) void k2_route_all(
    const unsigned short* __restrict__ znbA, const unsigned short* __restrict__ znbB,
    const float* __restrict__ W1, const float* __restrict__ b1,
    float* __restrict__ acc, int* __restrict__ flags,
    float* __restrict__ out, int n_neigh)
{
    const int n_rows = n_neigh + 1;
    const int tid  = threadIdx.x;
    const int lane = tid & 63;
    const int wv   = tid >> 6;
    const int side = blockIdx.x & 1;
    const int bg   = blockIdx.x >> 1;
    const unsigned short* __restrict__ zA = znbA + (size_t)side * n_rows * 64;
    const unsigned short* __restrict__ zB = znbB + (size_t)side * n_rows * 64;

    __shared__ float sW[4096];   // W1 i-major: sW[i*64 + m]
    __shared__ float red[16][64];
    __shared__ float sEgo[64];
    __shared__ float sTmp[64];

    for (int q = tid; q < 4096; q += 1024) {
        const int i = q >> 6, m = q & 63;
        sW[q] = W1[(m >> 4) * 1024 + i * 16 + (m & 15)];
    }
    if (tid < 64) sEgo[tid] = bf2f(zA[tid]) * LOG2E;  // normalized row 0
    __syncthreads();

    const int j   = lane & 7;
    const int rg0 = bg * 128 + (tid >> 3);   // this block's first row offset

    for (int s = 0; s < 6; ++s) {
        const unsigned short* __restrict__ zb = (s < 3) ? zA : zB;
        float ego[8];
#pragma unroll
        for (int m = 0; m < 8; ++m) ego[m] = sEgo[j * 8 + m];

        float a8[8] = {0.f, 0.f, 0.f, 0.f, 0.f, 0.f, 0.f, 0.f};
        for (int r = rg0; r < n_neigh; r += SPB * 128) {
            const uint4 q = *(const uint4*)(zb + (((size_t)r + 1) << 6) + (j << 3));
            float x[8];
            x[0] = bflo(q.x); x[1] = bfhi(q.x);
            x[2] = bflo(q.y); x[3] = bfhi(q.y);
            x[4] = bflo(q.z); x[5] = bfhi(q.z);
            x[6] = bflo(q.w); x[7] = bfhi(q.w);
            float partial = 0.f;
#pragma unroll
            for (int m = 0; m < 8; ++m) partial = fmaf(x[m], ego[m], partial);
            const float dp = partial + __shfl_xor(partial, 1, 64);  // ch dot * log2e
            const float eo = exp2f(dp);
            float den = eo + __shfl_xor(eo, 2, 64);
            den += __shfl_xor(den, 4, 64);                          // all 4 channels
            const float p = eo * __builtin_amdgcn_rcpf(den);
#pragma unroll
            for (int m = 0; m < 8; ++m) a8[m] = fmaf(p, x[m], a8[m]);
        }
#pragma unroll
        for (int mask = 8; mask <= 32; mask <<= 1)
#pragma unroll
            for (int m = 0; m < 8; ++m) a8[m] += __shfl_xor(a8[m], mask, 64);
        if (lane < 8) {
#pragma unroll
            for (int m = 0; m < 8; ++m) red[wv][lane * 8 + m] = a8[m];
        }
        __syncthreads();                                  // (1) red complete

        float* slotbase = acc + (size_t)(s * 2 + side) * SPB * 64;
        int*   flagbase = flags + (s * 2 + side) * SPB;
        if (wv == 0) {
            float ssum = 0.f;
#pragma unroll
            for (int w = 0; w < 16; ++w) ssum += red[w][lane];
            atomicExch(&slotbase[bg * 64 + lane], ssum);  // overwrite: replay-safe
            __threadfence();                              // wave-wide vmem drain
            if (lane == 0) atomicExch(&flagbase[bg], 1);
        }
        __syncthreads();                                  // (2) red reusable

        if (s < 5) {
            if (wv < SPB) {
                if (lane == 0)
                    while (atomicAdd(&flagbase[wv], 0) == 0) __builtin_amdgcn_s_sleep(1);
                red[wv][lane] = rmwf(&slotbase[wv * 64 + lane]);  // parallel reads
            }
            __syncthreads();                              // (3) partials in LDS
            if (wv == 0) {
                float e = 0.f;
#pragma unroll
                for (int bb = 0; bb < SPB; ++bb) e += red[bb][lane];
                if (s == 2) sTmp[lane] = e;               // raw routed L0
                else sEgo[lane] = (e / fmaxf(sqrtf(g16sum(e * e)), EPS)) * LOG2E;
            }
            __syncthreads();                              // (4) ego ready
            if (s == 2) {
                if (wv == 0) {                            // row-0 proj(W1)
                    float xa[4];
#pragma unroll
                    for (int jj = 0; jj < 4; ++jj) xa[jj] = sTmp[((lane & 15) << 2) | jj];
                    float sum = b1[lane];
#pragma unroll
                    for (int i = 0; i < 64; ++i)
                        sum = fmaf(__shfl(xa[i & 3], i >> 2, 64), sW[i * 64 + lane], sum);
                    sum = fmaxf(sum, 0.f);
                    sEgo[lane] = (sum / fmaxf(sqrtf(g16sum(sum * sum)), EPS)) * LOG2E;
                }
                __syncthreads();                          // (5)
            }
        } else if (side == 0 && bg == 0) {
            // finalize: 16 waves poll+read all 16 s=5 partials (both sides)
            const int s2 = wv >> 3, bb = wv & 7;
            float* sb2 = acc + (size_t)(5 * 2 + s2) * SPB * 64;
            int*   fb2 = flags + (5 * 2 + s2) * SPB;
            if (lane == 0)
                while (atomicAdd(&fb2[bb], 0) == 0) __builtin_amdgcn_s_sleep(1);
            red[wv][lane] = rmwf(&sb2[bb * 64 + lane]);
            __syncthreads();
            if (wv == 0) {
                float u = 0.f, v = 0.f;
#pragma unroll
                for (int w = 0; w < 8; ++w)  u += red[w][lane];
#pragma unroll
                for (int w = 8; w < 16; ++w) v += red[w][lane];
                out[1 + lane]  = u;
                out[65 + lane] = v;
                float p = u * v;
#pragma unroll
                for (int sh = 32; sh >= 1; sh >>= 1) p += __shfl_xor(p, sh, 64);
                if (lane == 0) out[0] = p;
            }
        }
    }
}

extern "C" void kernel_launch(void* const* d_in, const int* in_sizes, int n_in,
                              void* d_out, int out_size, void* d_ws, size_t ws_size,
                              hipStream_t stream) {
    const int*   user       = (const int*)d_in[0];
    const int*   item       = (const int*)d_in[1];
    const int*   neigh_user = (const int*)d_in[2];
    const int*   neigh_item = (const int*)d_in[3];
    const float* Gu         = (const float*)d_in[4];
    const float* Gi         = (const float*)d_in[5];
    const float* W0         = (const float*)d_in[6];
    const float* b0         = (const float*)d_in[7];
    const float* W1         = (const float*)d_in[8];
    const float* b1         = (const float*)d_in[9];
    float* out = (float*)d_out;

    const int n_neigh = in_sizes[2];
    const int n_rows  = n_neigh + 1;
    const size_t rowsz = (size_t)2 * n_rows * 64;

    unsigned short* znbA = (unsigned short*)d_ws;
    unsigned short* znbB = znbA + rowsz;
    float*          acc  = (float*)(znbB + rowsz);
    int*            flags = (int*)(acc + 6 * 2 * SPB * 64);

    hipLaunchKernelGGL(k1_gather_proj2, dim3((2 * n_rows + 3) / 4), dim3(256), 0, stream,
                       user, item, neigh_user, neigh_item, Gu, Gi, W0, b0, W1, b1,
                       znbA, znbB, flags, n_rows);
    hipLaunchKernelGGL(k2_route_all, dim3(NBK), dim3(1024), 0, stream,
                       znbA, znbB, W1, b1, acc, flags, out, n_neigh);
}

// Round 14
// 45.463 us; speedup vs baseline: 4.6571x; 1.0967x over previous
//
#include <hip/hip_runtime.h>
#include <hip/hip_bf16.h>

// DisenGCN forward — 2-dispatch chain, 8-blocks/side routing, gen-tagged sync:
//   K1 (chip-wide): gather -> z0=proj(W0) -> znbA [bf16 norm]; neighbors also
//                   z1=proj(W1,z0) -> znbB [bf16 norm]. Bumps call_ctr.
//   K2 (16 blocks = 8/side x 1024 thr): 6 routing sweeps. Per sweep:
//       block partial -> ONE atomicExch(u64{payload,gen}) per lane into own
//       slot; readers (waves 0..7) poll their element with a u64 RMW-read
//       until lo==gen — payload rides the poll. No fence, no flags, no
//       pre-zeroing: gen = call_ctr*8+s+1 is fresh every call/replay.
//       s==2: row-0 proj(W1). s==5: block(0,0) polls all 16 slots, finalizes.
//
// Cross-block rules (R4..R13-verified): atomic writes + atomic RMW reads.
// Plain loads cross blocks only at dispatch boundaries (znbA/znbB, call_ctr).
//
// Route layout: 8 lanes/row; lane j=lane&7 holds elems [8j..8j+7]; channel
// k=j>>1. Ego in sEgo normalized AND pre-scaled by log2(e) (exp2 softmax).
//
// ws: znbA[2*n_rows*64 bf16] | znbB[same] | slots[6*2*SPB*64 u64] | call_ctr[int]

#define EPS 1e-12f
#define LOG2E 1.44269504088896f
#define SPB 8              // blocks per side in K2
#define NBK (2 * SPB)

__device__ __forceinline__ float g16sum(float v) {
    v += __shfl_xor(v, 1, 64);
    v += __shfl_xor(v, 2, 64);
    v += __shfl_xor(v, 4, 64);
    v += __shfl_xor(v, 8, 64);
    return v;
}
__device__ __forceinline__ unsigned short f2bf(float f) {  // RNE
    unsigned int b = __float_as_uint(f);
    b += 0x7fffu + ((b >> 16) & 1u);
    return (unsigned short)(b >> 16);
}
__device__ __forceinline__ float bf2f(unsigned short u) {
    return __uint_as_float(((unsigned int)u) << 16);
}
__device__ __forceinline__ float bflo(unsigned int w) {
    return __uint_as_float(w << 16);
}
__device__ __forceinline__ float bfhi(unsigned int w) {
    return __uint_as_float(w & 0xffff0000u);
}

__device__ __forceinline__ void slot_write(unsigned long long* p, float v,
                                           unsigned int gen) {
    atomicExch(p, ((unsigned long long)__float_as_uint(v) << 32) |
                  (unsigned long long)gen);
}
__device__ __forceinline__ float slot_read(unsigned long long* p,
                                           unsigned int gen) {
    unsigned long long v;
    for (;;) {
        v = atomicAdd(p, 0ull);                       // 64-bit RMW read
        if ((unsigned int)(v & 0xffffffffull) == gen) break;
        __builtin_amdgcn_s_sleep(1);
    }
    return __uint_as_float((unsigned int)(v >> 32));
}

__device__ __forceinline__ float proj_row4(const float xa[4],
                                           const float* __restrict__ W,
                                           const float* __restrict__ b, int lane) {
    const int k = lane >> 4, d = lane & 15;
    float sum = b[k * 16 + d];
    const float* __restrict__ Wp = W + k * 1024 + d;  // W[k][i][d]
#pragma unroll
    for (int i = 0; i < 64; ++i)
        sum = fmaf(__shfl(xa[i & 3], i >> 2, 64), Wp[i * 16], sum);
    return fmaxf(sum, 0.f);
}

// ---- K1: gather + proj L0 + (neighbors) proj L1; bump call_ctr ----
__global__ __launch_bounds__(256) void k1_gather_proj2(
    const int* __restrict__ user, const int* __restrict__ item,
    const int* __restrict__ nu, const int* __restrict__ ni,
    const float* __restrict__ Gu, const float* __restrict__ Gi,
    const float* __restrict__ W0, const float* __restrict__ b0,
    const float* __restrict__ W1, const float* __restrict__ b1,
    unsigned short* __restrict__ znbA, unsigned short* __restrict__ znbB,
    unsigned int* __restrict__ call_ctr, int n_rows)
{
    if (blockIdx.x == 0 && threadIdx.x == 0) atomicAdd(call_ctr, 1u);

    const int lane = threadIdx.x & 63;
    const int wv   = threadIdx.x >> 6;
    const int rr   = blockIdx.x * 4 + wv;
    if (rr >= 2 * n_rows) return;
    const int side = rr >= n_rows;
    const int n    = rr - side * n_rows;
    const int c    = lane & 15;

    int idx; const float* G;
    if (n == 0) { idx = side ? item[0] : user[0];     G = side ? Gi : Gu; }
    else        { idx = side ? ni[n - 1] : nu[n - 1]; G = side ? Gu : Gi; }
    const float4 xv = ((const float4*)(G + (size_t)idx * 64))[c];
    const float xa[4] = {xv.x, xv.y, xv.z, xv.w};

    const float z0 = proj_row4(xa, W0, b0, lane);
    const float nrm0 = fmaxf(sqrtf(g16sum(z0 * z0)), EPS);
    znbA[(size_t)rr * 64 + lane] = f2bf(z0 / nrm0);

    if (n == 0) return;  // row 0's L1 input is the routed result (K2)

    float xa2[4];
#pragma unroll
    for (int jj = 0; jj < 4; ++jj) xa2[jj] = __shfl(z0, (c << 2) | jj, 64);
    const float z1 = proj_row4(xa2, W1, b1, lane);
    const float nrm1 = fmaxf(sqrtf(g16sum(z1 * z1)), EPS);
    znbB[(size_t)rr * 64 + lane] = f2bf(z1 / nrm1);
}

// ---- K2: 6 routing sweeps across 8 blocks/side + fused finalize ----
__global__ __launch_bounds__(1024) void k2_route_all(
    const unsigned short* __restrict__ znbA, const unsigned short* __restrict__ znbB,
    const float* __restrict__ W1, const float* __restrict__ b1,
    unsigned long long* __restrict__ slots,
    const unsigned int* __restrict__ call_ctr,
    float* __restrict__ out, int n_neigh)
{
    const int n_rows = n_neigh + 1;
    const int tid  = threadIdx.x;
    const int lane = tid & 63;
    const int wv   = tid >> 6;
    const int side = blockIdx.x & 1;
    const int bg   = blockIdx.x >> 1;
    const unsigned short* __restrict__ zA = znbA + (size_t)side * n_rows * 64;
    const unsigned short* __restrict__ zB = znbB + (size_t)side * n_rows * 64;
    const unsigned int genbase = (*call_ctr) * 8u;   // dispatch-boundary read

    __shared__ float sW[4096];   // W1 i-major: sW[i*64 + m]
    __shared__ float red[16][64];
    __shared__ float sEgo[64];
    __shared__ float sTmp[64];

    for (int q = tid; q < 4096; q += 1024) {
        const int i = q >> 6, m = q & 63;
        sW[q] = W1[(m >> 4) * 1024 + i * 16 + (m & 15)];
    }
    if (tid < 64) sEgo[tid] = bf2f(zA[tid]) * LOG2E;  // normalized row 0
    __syncthreads();

    const int j   = lane & 7;
    const int rg0 = bg * 128 + (tid >> 3);   // this block's first row offset

    for (int s = 0; s < 6; ++s) {
        const unsigned short* __restrict__ zb = (s < 3) ? zA : zB;
        const unsigned int gen = genbase + (unsigned int)s + 1u;
        float ego[8];
#pragma unroll
        for (int m = 0; m < 8; ++m) ego[m] = sEgo[j * 8 + m];

        float a8[8] = {0.f, 0.f, 0.f, 0.f, 0.f, 0.f, 0.f, 0.f};
        for (int r = rg0; r < n_neigh; r += SPB * 128) {
            const uint4 q = *(const uint4*)(zb + (((size_t)r + 1) << 6) + (j << 3));
            float x[8];
            x[0] = bflo(q.x); x[1] = bfhi(q.x);
            x[2] = bflo(q.y); x[3] = bfhi(q.y);
            x[4] = bflo(q.z); x[5] = bfhi(q.z);
            x[6] = bflo(q.w); x[7] = bfhi(q.w);
            float partial = 0.f;
#pragma unroll
            for (int m = 0; m < 8; ++m) partial = fmaf(x[m], ego[m], partial);
            const float dp = partial + __shfl_xor(partial, 1, 64);  // ch dot * log2e
            const float eo = exp2f(dp);
            float den = eo + __shfl_xor(eo, 2, 64);
            den += __shfl_xor(den, 4, 64);                          // all 4 channels
            const float p = eo * __builtin_amdgcn_rcpf(den);
#pragma unroll
            for (int m = 0; m < 8; ++m) a8[m] = fmaf(p, x[m], a8[m]);
        }
#pragma unroll
        for (int mask = 8; mask <= 32; mask <<= 1)
#pragma unroll
            for (int m = 0; m < 8; ++m) a8[m] += __shfl_xor(a8[m], mask, 64);
        if (lane < 8) {
#pragma unroll
            for (int m = 0; m < 8; ++m) red[wv][lane * 8 + m] = a8[m];
        }
        __syncthreads();                                  // (1) red complete

        unsigned long long* slotbase = slots + (size_t)(s * 2 + side) * SPB * 64;
        if (wv == 0) {
            float ssum = 0.f;
#pragma unroll
            for (int w = 0; w < 16; ++w) ssum += red[w][lane];
            slot_write(&slotbase[bg * 64 + lane], ssum, gen);  // one exch, self-validating
        }
        __syncthreads();                                  // (2) red reusable

        if (s < 5) {
            if (wv < SPB)
                red[wv][lane] = slot_read(&slotbase[wv * 64 + lane], gen);
            __syncthreads();                              // (3) partials in LDS
            if (wv == 0) {
                float e = 0.f;
#pragma unroll
                for (int bb = 0; bb < SPB; ++bb) e += red[bb][lane];
                if (s == 2) sTmp[lane] = e;               // raw routed L0
                else sEgo[lane] = (e / fmaxf(sqrtf(g16sum(e * e)), EPS)) * LOG2E;
            }
            __syncthreads();                              // (4) ego ready
            if (s == 2) {
                if (wv == 0) {                            // row-0 proj(W1)
                    float xa[4];
#pragma unroll
                    for (int jj = 0; jj < 4; ++jj) xa[jj] = sTmp[((lane & 15) << 2) | jj];
                    float sum = b1[lane];
#pragma unroll
                    for (int i = 0; i < 64; ++i)
                        sum = fmaf(__shfl(xa[i & 3], i >> 2, 64), sW[i * 64 + lane], sum);
                    sum = fmaxf(sum, 0.f);
                    sEgo[lane] = (sum / fmaxf(sqrtf(g16sum(sum * sum)), EPS)) * LOG2E;
                }
                __syncthreads();                          // (5)
            }
        } else if (side == 0 && bg == 0) {
            // finalize: 16 waves poll+read all 16 s=5 partials (both sides)
            const int s2 = wv >> 3, bb = wv & 7;
            unsigned long long* sb2 = slots + (size_t)(5 * 2 + s2) * SPB * 64;
            red[wv][lane] = slot_read(&sb2[bb * 64 + lane], gen);
            __syncthreads();
            if (wv == 0) {
                float u = 0.f, v = 0.f;
#pragma unroll
                for (int w = 0; w < 8; ++w)  u += red[w][lane];
#pragma unroll
                for (int w = 8; w < 16; ++w) v += red[w][lane];
                out[1 + lane]  = u;
                out[65 + lane] = v;
                float p = u * v;
#pragma unroll
                for (int sh = 32; sh >= 1; sh >>= 1) p += __shfl_xor(p, sh, 64);
                if (lane == 0) out[0] = p;
            }
        }
    }
}

extern "C" void kernel_launch(void* const* d_in, const int* in_sizes, int n_in,
                              void* d_out, int out_size, void* d_ws, size_t ws_size,
                              hipStream_t stream) {
    const int*   user       = (const int*)d_in[0];
    const int*   item       = (const int*)d_in[1];
    const int*   neigh_user = (const int*)d_in[2];
    const int*   neigh_item = (const int*)d_in[3];
    const float* Gu         = (const float*)d_in[4];
    const float* Gi         = (const float*)d_in[5];
    const float* W0         = (const float*)d_in[6];
    const float* b0         = (const float*)d_in[7];
    const float* W1         = (const float*)d_in[8];
    const float* b1         = (const float*)d_in[9];
    float* out = (float*)d_out;

    const int n_neigh = in_sizes[2];
    const int n_rows  = n_neigh + 1;
    const size_t rowsz = (size_t)2 * n_rows * 64;

    unsigned short*     znbA  = (unsigned short*)d_ws;
    unsigned short*     znbB  = znbA + rowsz;
    unsigned long long* slots = (unsigned long long*)(znbB + rowsz);
    unsigned int*       ctr   = (unsigned int*)(slots + 6 * 2 * SPB * 64);

    hipLaunchKernelGGL(k1_gather_proj2, dim3((2 * n_rows + 3) / 4), dim3(256), 0, stream,
                       user, item, neigh_user, neigh_item, Gu, Gi, W0, b0, W1, b1,
                       znbA, znbB, ctr, n_rows);
    hipLaunchKernelGGL(k2_route_all, dim3(NBK), dim3(1024), 0, stream,
                       znbA, znbB, W1, b1, slots, ctr, out, n_neigh);
}